// Round 6
// baseline (1225.330 us; speedup 1.0000x reference)
//
#include <hip/hip_runtime.h>
#include <hip/hip_bf16.h>
#include <cstdint>
#include <cstddef>

#define NN 10000
#define NE 160000

typedef unsigned short u16;

__device__ __forceinline__ float b2f(u16 u){
    union { uint32_t i; float f; } v; v.i = ((uint32_t)u) << 16; return v.f;
}
__device__ __forceinline__ u16 f2b(float f){
    union { __hip_bfloat16 h; u16 u; } c; c.h = __float2bfloat16(f); return c.u;
}
__device__ __forceinline__ float silu_f(float x){ return x / (1.f + __expf(-x)); }

// ---------------- workspace layout (4-byte word offsets) ----------------
constexpr size_t W_FLAG = 0;                        // 16
constexpr size_t W_CNT  = 16;                       // 10000
constexpr size_t W_OFFS = 10016;                    // 10001
constexpr size_t W_CUR  = 20032;                    // 10000
constexpr size_t W_ORD  = 30032;                    // 160000
constexpr size_t W_SSND = 190032;                   // 160000
constexpr size_t W_ATT  = 350032;                   // 100000
constexpr size_t W_POS  = 450032;                   // 30000
constexpr size_t W_SHF  = 480032;                   // 480000
constexpr size_t W_WGT  = 960032;
constexpr size_t OW_EMB = 0;
constexpr size_t OW_UP0 = 640;
constexpr size_t OW_R10 = 4736;
constexpr size_t OW_R20 = 5248;
constexpr size_t OW_R30 = 9344;
constexpr size_t OW_MIX0= 25728;
constexpr size_t OW_SC0 = 42112;
constexpr size_t OW_PR0 = 83072;
constexpr size_t OW_UP1 = 83264;
constexpr size_t OW_R11 = 87360;
constexpr size_t OW_R21 = 87872;
constexpr size_t OW_R31 = 91968;
constexpr size_t OW_MIX1= 108352;
constexpr size_t OW_SC1 = 124736;
constexpr size_t OW_PR1 = 165696;
constexpr size_t OW_RD0 = 165888;
constexpr size_t OW_ML1 = 165952;
constexpr size_t OW_ML2 = 166976;
// transposed radial weights (for edge-parallel MLP)
constexpr size_t OW_W1T0 = 166992;   // [64][8]
constexpr size_t OW_W2T0 = 167504;   // [64][64]
constexpr size_t OW_W3T0 = 171600;   // [64][64] (l'=0 slice)
constexpr size_t OW_W1T1 = 175696;
constexpr size_t OW_W2T1 = 176208;
constexpr size_t OW_W3T1 = 180304;
constexpr size_t OW_TEND = 184400;
constexpr size_t W_BES  = W_WGT + OW_TEND;          // [E,8] f32
constexpr size_t W_NF0  = W_BES + (size_t)NE*8;     // [N,64]
constexpr size_t W_H    = W_NF0 + (size_t)NN*64;
constexpr size_t W_A    = W_H   + (size_t)NN*64;
constexpr size_t W_NF1  = W_A   + (size_t)NN*64;
constexpr size_t W_R    = W_NF1 + (size_t)NN*64;    // R buffer (tiered), RECEIVER-SORTED

constexpr size_t NEED_BF16 = (W_R + (size_t)NE*32) * 4;  // ~40.4 MB
constexpr size_t NEED_F32  = (W_R + (size_t)NE*64) * 4;  // ~60.9 MB

// ---------------- dtype detection via exact one-hot structure of attrs ----------------
__global__ void k_detect(const uint32_t* __restrict__ attrs, int* __restrict__ flag){
    __shared__ int cnt_s;
    if (threadIdx.x == 0) cnt_s = 0;
    __syncthreads();
    int c = 0;
    for (int i = threadIdx.x; i < 50000; i += 256){
        uint32_t v = attrs[i];
        if (v != 0u && v != 0x3F800000u) c++;
    }
    atomicAdd(&cnt_s, c);
    __syncthreads();
    if (threadIdx.x == 0) flag[0] = (cnt_s > 100) ? 1 : 0;   // 1 = inputs are bf16
}

// ---------------- convert all float inputs -> fp32 workspace ----------------
struct PrepArgs { const void* s[21]; float* d[21]; int n[21]; };
__global__ void k_prep(PrepArgs a, const int* __restrict__ flag){
    int bf = flag[0];
    int stride = gridDim.x * blockDim.x;
    int t0 = blockIdx.x * blockDim.x + threadIdx.x;
    for (int k = 0; k < 21; k++){
        float* d = a.d[k]; int n = a.n[k];
        if (bf){
            const u16* s = (const u16*)a.s[k];
            for (int i = t0; i < n; i += stride) d[i] = b2f(s[i]);
        } else {
            const float* s = (const float*)a.s[k];
            for (int i = t0; i < n; i += stride) d[i] = s[i];
        }
    }
}

// ---------------- transpose radial weights (both interactions in one launch) ----------------
__global__ void k_wprep(const float* __restrict__ Wg, float* __restrict__ Wt){
    // block 0: interaction 0, block 1: interaction 1
    const float* W1 = Wg + (blockIdx.x ? OW_R11 : OW_R10);
    const float* W2 = Wg + (blockIdx.x ? OW_R21 : OW_R20);
    const float* W3 = Wg + (blockIdx.x ? OW_R31 : OW_R30);
    float* W1T = Wt + (blockIdx.x ? OW_W1T1 : OW_W1T0);
    float* W2T = Wt + (blockIdx.x ? OW_W2T1 : OW_W2T0);
    float* W3T = Wt + (blockIdx.x ? OW_W3T1 : OW_W3T0);
    int t = threadIdx.x;
    for (int i = t; i < 512;  i += 256){ int r = i >> 6, f = i & 63; W1T[f*8  + r] = W1[r*64 + f]; }
    for (int i = t; i < 4096; i += 256){ int r = i >> 6, f = i & 63; W2T[f*64 + r] = W2[r*64 + f]; }
    for (int i = t; i < 4096; i += 256){ int r = i >> 6, f = i & 63; W3T[f*64 + r] = W3[r*256 + 4*f]; }
}

// ---------------- edge bessel features ----------------
__global__ void k_geom(const float* __restrict__ pos, const float* __restrict__ shf,
                       const int* __restrict__ snd, const int* __restrict__ rcv,
                       float* __restrict__ bess){
    int e = blockIdx.x * 256 + threadIdx.x;
    if (e >= NE) return;
    int s = snd[e], r = rcv[e];
    float vx = pos[r*3+0] - pos[s*3+0] + shf[e*3+0];
    float vy = pos[r*3+1] - pos[s*3+1] + shf[e*3+1];
    float vz = pos[r*3+2] - pos[s*3+2] + shf[e*3+2];
    float rr = sqrtf(vx*vx + vy*vy + vz*vz);
    float xr = rr * 0.1f;
    float x2 = xr*xr; float x5 = x2*x2*xr;
    float env = 1.f - 21.f*x5 + 35.f*x5*xr - 15.f*x5*x2;
    if (xr >= 1.f) env = 0.f;
    float scl = 0.4472135954999579f * env / (rr + 1e-9f);
    float* be = bess + (size_t)e*8;
    #pragma unroll
    for (int n = 1; n <= 8; n++)
        be[n-1] = scl * sinf((float)n * 3.14159265358979323846f * rr * 0.1f);
}

// ---------------- CSR build ----------------
__global__ void k_hist(const int* __restrict__ rcv, int* __restrict__ cnt){
    int e = blockIdx.x * 256 + threadIdx.x;
    if (e < NE) atomicAdd(&cnt[rcv[e]], 1);
}
__global__ void k_scan(const int* __restrict__ cnt, int* __restrict__ offs, int* __restrict__ cur){
    __shared__ int part[1024];
    int t = threadIdx.x;
    int base = t * 10;
    int s = 0;
    for (int i = 0; i < 10; i++) if (base + i < NN) s += cnt[base + i];
    part[t] = s; __syncthreads();
    for (int d = 1; d < 1024; d <<= 1){
        int v = part[t];
        if (t >= d) v += part[t - d];
        __syncthreads();
        part[t] = v;
        __syncthreads();
    }
    int run = part[t] - s;
    for (int i = 0; i < 10; i++){
        int idx = base + i;
        if (idx < NN){ offs[idx] = run; cur[idx] = run; run += cnt[idx]; }
    }
    if (t == 1023) offs[NN] = part[1023];
}
__global__ void k_scatter(const int* __restrict__ rcv, const int* __restrict__ snd,
                          int* __restrict__ cur, int* __restrict__ order, int* __restrict__ ssnd){
    int e = blockIdx.x * 256 + threadIdx.x;
    if (e < NE){
        int p = atomicAdd(&cur[rcv[e]], 1);
        order[p] = e;
        ssnd[p]  = snd[e];
    }
}

// ---------------- nf0 = attrs @ w_embed ----------------
__global__ void k_embed(const float* __restrict__ attrs, const float* __restrict__ Wemb,
                        float* __restrict__ nf0){
    int t = blockIdx.x * 256 + threadIdx.x;
    int n = t >> 6;
    int l = t & 63;
    float acc = 0.f;
    #pragma unroll
    for (int s = 0; s < 10; s++) acc += attrs[n*10 + s] * Wemb[s*64 + l];
    nf0[n*64 + l] = acc;
}

// ---------------- h = nf(:,:,0) @ W_up ----------------
__global__ void k_h(const float* __restrict__ src, const float* __restrict__ W,
                    float* __restrict__ h){
    int t = blockIdx.x * 256 + threadIdx.x;
    int n = t >> 6;
    int l = t & 63;
    const float* row = src + (size_t)n*64;
    float acc = 0.f;
    #pragma unroll 8
    for (int g = 0; g < 64; g++) acc += row[g] * W[g*64 + l];
    h[n*64 + l] = acc;
}

// ---------------- edge-parallel radial MLP: thread = sorted position p ----------------
// FULLY UNROLLED: all h1/h2 indices compile-time -> registers, no scratch.
// Weights wave-uniform + constant offsets -> scalar loads.
template<int RF32>
__global__ __launch_bounds__(256, 1) void k_mlp(const int* __restrict__ order,
        const float* __restrict__ bess,
        const float* __restrict__ W1T, const float* __restrict__ W2T,
        const float* __restrict__ W3T, void* __restrict__ Rout){
    int p = blockIdx.x * 256 + threadIdx.x;   // NE = 625*256 exact
    int e = order[p];
    float4 q0 = *(const float4*)(bess + (size_t)e*8);
    float4 q1 = *(const float4*)(bess + (size_t)e*8 + 4);
    float h1[64];
    #pragma unroll
    for (int f = 0; f < 64; f++){
        float a = q0.x*W1T[f*8+0] + q0.y*W1T[f*8+1] + q0.z*W1T[f*8+2] + q0.w*W1T[f*8+3]
                + q1.x*W1T[f*8+4] + q1.y*W1T[f*8+5] + q1.z*W1T[f*8+6] + q1.w*W1T[f*8+7];
        h1[f] = silu_f(a);
    }
    float h2[64];
    #pragma unroll
    for (int f = 0; f < 64; f++){
        float a0 = 0.f, a1 = 0.f, a2 = 0.f, a3 = 0.f;
        #pragma unroll
        for (int j = 0; j < 64; j += 4){
            a0 += h1[j+0] * W2T[f*64 + j+0];
            a1 += h1[j+1] * W2T[f*64 + j+1];
            a2 += h1[j+2] * W2T[f*64 + j+2];
            a3 += h1[j+3] * W2T[f*64 + j+3];
        }
        h2[f] = silu_f((a0+a1) + (a2+a3));
    }
    #pragma unroll
    for (int f0 = 0; f0 < 64; f0 += 4){
        float r[4];
        #pragma unroll
        for (int k = 0; k < 4; k++){
            int f = f0 + k;
            float a0 = 0.f, a1 = 0.f, a2 = 0.f, a3 = 0.f;
            #pragma unroll
            for (int j = 0; j < 64; j += 4){
                a0 += h2[j+0] * W3T[f*64 + j+0];
                a1 += h2[j+1] * W3T[f*64 + j+1];
                a2 += h2[j+2] * W3T[f*64 + j+2];
                a3 += h2[j+3] * W3T[f*64 + j+3];
            }
            r[k] = (a0+a1) + (a2+a3);
        }
        if (RF32){
            *(float4*)((float*)Rout + (size_t)p*64 + f0) = make_float4(r[0], r[1], r[2], r[3]);
        } else {
            uint32_t lo = ((uint32_t)f2b(r[1]) << 16) | f2b(r[0]);
            uint32_t hi = ((uint32_t)f2b(r[3]) << 16) | f2b(r[2]);
            *(uint2*)((u16*)Rout + (size_t)p*64 + f0) = make_uint2(lo, hi);
        }
    }
}

// ---------------- CSR gather-sum: A[n,f] = (1/16) sum_p h[ssnd[p],f] * R[p,f] ----------------
// R is receiver-sorted -> sequential streaming; only h rows (2.5 MB, L2) are gathered.
template<int RF32>
__global__ __launch_bounds__(256) void k_gather(const int* __restrict__ offs,
        const int* __restrict__ ssnd, const float* __restrict__ h,
        const void* __restrict__ R, float* __restrict__ A){
    int wv = threadIdx.x >> 6;
    int n  = blockIdx.x * 4 + wv;
    int l  = threadIdx.x & 63;
    int beg = __builtin_amdgcn_readfirstlane(offs[n]);
    int end = __builtin_amdgcn_readfirstlane(offs[n+1]);
    float acc = 0.f;
    int p = beg;
    for (; p + 4 <= end; p += 4){
        int s0 = __builtin_amdgcn_readfirstlane(ssnd[p+0]);
        int s1 = __builtin_amdgcn_readfirstlane(ssnd[p+1]);
        int s2 = __builtin_amdgcn_readfirstlane(ssnd[p+2]);
        int s3 = __builtin_amdgcn_readfirstlane(ssnd[p+3]);
        float r0, r1, r2, r3;
        if (RF32){
            const float* Rf = (const float*)R;
            r0 = Rf[(size_t)(p+0)*64 + l];
            r1 = Rf[(size_t)(p+1)*64 + l];
            r2 = Rf[(size_t)(p+2)*64 + l];
            r3 = Rf[(size_t)(p+3)*64 + l];
        } else {
            const u16* Rb = (const u16*)R;
            r0 = b2f(Rb[(size_t)(p+0)*64 + l]);
            r1 = b2f(Rb[(size_t)(p+1)*64 + l]);
            r2 = b2f(Rb[(size_t)(p+2)*64 + l]);
            r3 = b2f(Rb[(size_t)(p+3)*64 + l]);
        }
        float h0v = h[s0*64 + l];
        float h1v = h[s1*64 + l];
        float h2v = h[s2*64 + l];
        float h3v = h[s3*64 + l];
        acc += h0v*r0 + h1v*r1 + h2v*r2 + h3v*r3;
    }
    for (; p < end; p++){
        int s = __builtin_amdgcn_readfirstlane(ssnd[p]);
        float rv;
        if (RF32) rv = ((const float*)R)[(size_t)p*64 + l];
        else      rv = b2f(((const u16*)R)[(size_t)p*64 + l]);
        acc += h[s*64 + l] * rv;
    }
    A[n*64 + l] = acc * 0.0625f;
}

// ---------------- legacy fused msg (fallback when ws too small for R buffer) ----------------
__global__ __launch_bounds__(256) void k_msg_fused(const int* __restrict__ offs, const int* __restrict__ order,
        const int* __restrict__ snd, const float* __restrict__ h, const float* __restrict__ bess,
        const float* __restrict__ W1, const float* __restrict__ W2, const float* __restrict__ W3,
        float* __restrict__ A){
    int wv = threadIdx.x >> 6;
    int n  = blockIdx.x * 4 + wv;
    int l  = threadIdx.x & 63;
    float w1c[8];
    #pragma unroll
    for (int i = 0; i < 8; i++) w1c[i] = W1[i*64 + l];
    float w2c[64];
    #pragma unroll
    for (int j = 0; j < 64; j++) w2c[j] = W2[j*64 + l];
    float w3c[64];
    #pragma unroll
    for (int j = 0; j < 64; j++) w3c[j] = W3[j*256 + 4*l];
    float acc = 0.f;
    int beg = __builtin_amdgcn_readfirstlane(offs[n]);
    int end = __builtin_amdgcn_readfirstlane(offs[n+1]);
    for (int p = beg; p < end; p++){
        int e = __builtin_amdgcn_readfirstlane(order[p]);
        int s = __builtin_amdgcn_readfirstlane(snd[e]);
        const float* be = bess + (size_t)e*8;
        float h1 = 0.f;
        #pragma unroll
        for (int i = 0; i < 8; i++) h1 += be[i] * w1c[i];
        h1 = silu_f(h1);
        float h2 = 0.f;
        #pragma unroll
        for (int j = 0; j < 64; j++) h2 += __shfl(h1, j) * w2c[j];
        h2 = silu_f(h2);
        float r = 0.f;
        #pragma unroll
        for (int j = 0; j < 64; j++) r += __shfl(h2, j) * w3c[j];
        acc += h[s*64 + l] * r;
    }
    A[n*64 + l] = acc * 0.0625f;
}

// ---------------- node update (mix k=0 + sc + poly) + readout ----------------
template<int LAST>
__global__ __launch_bounds__(256) void k_node(const float* __restrict__ A, const float* __restrict__ nf,
        const float* __restrict__ attrs, const float* __restrict__ Wmix0, const float* __restrict__ Wsc,
        const float* __restrict__ Wprod, const float* __restrict__ Wtail, const float* __restrict__ Wml2,
        float* __restrict__ nf1out, void* __restrict__ out, const int* __restrict__ flag){
    int wv = threadIdx.x >> 6;
    int n  = blockIdx.x * 4 + wv;
    int l  = threadIdx.x & 63;
    float Af  = A[n*64 + l];
    float nff = nf[n*64 + l];
    float am = 0.f;
    #pragma unroll 16
    for (int f = 0; f < 64; f++) am += __shfl(Af, f) * Wmix0[f*64 + l];
    float sc = 0.f;
    for (int s = 0; s < 10; s++){
        float av = attrs[n*10 + s];       // wave-uniform
        if (av != 0.f){
            const float* Ws = Wsc + s*4096;
            float t = 0.f;
            #pragma unroll 16
            for (int f = 0; f < 64; f++) t += __shfl(nff, f) * Ws[f*64 + l];
            sc += av * t;
        }
    }
    float poly = Wprod[l] + Wprod[64 + l]*am + Wprod[128 + l]*am*am;
    float val = am*poly + sc;
    float rv;
    if (LAST == 0){
        nf1out[n*64 + l] = val;
        rv = val * Wtail[l];
    } else {
        // all 64 lanes run the shfl loop (shfl under divergence is UB on CDNA)
        int lj = l & 15;
        float t = 0.f;
        #pragma unroll 16
        for (int g = 0; g < 64; g++){
            float vg = __shfl(val, g);
            t += vg * Wtail[g*16 + lj];
        }
        rv = (l < 16) ? (silu_f(t) * Wml2[lj]) : 0.f;
    }
    #pragma unroll
    for (int o2 = 32; o2; o2 >>= 1) rv += __shfl_down(rv, o2);
    if (l == 0){
        int idx = 2*n + LAST;
        if (flag[0]) ((__hip_bfloat16*)out)[idx] = __float2bfloat16(rv);
        else         ((float*)out)[idx] = rv;
    }
}

// ---------------- launch ----------------
extern "C" void kernel_launch(void* const* d_in, const int* in_sizes, int n_in,
                              void* d_out, int out_size, void* d_ws, size_t ws_size,
                              hipStream_t stream) {
    int*   iw = (int*)d_ws;
    float* fw = (float*)d_ws;
    const int* snd = (const int*)d_in[3];
    const int* rcv = (const int*)d_in[4];

    PrepArgs pa;
    const int    pidx[21] = {0,1,2, 5,6,7,8,9,10,11,12,13,14,15,16,17,18,19,20,21,22};
    const size_t pdst[21] = {W_POS, W_ATT, W_SHF,
        W_WGT+OW_EMB, W_WGT+OW_UP0, W_WGT+OW_R10, W_WGT+OW_R20, W_WGT+OW_R30,
        W_WGT+OW_MIX0, W_WGT+OW_SC0, W_WGT+OW_PR0,
        W_WGT+OW_UP1, W_WGT+OW_R11, W_WGT+OW_R21, W_WGT+OW_R31,
        W_WGT+OW_MIX1, W_WGT+OW_SC1, W_WGT+OW_PR1,
        W_WGT+OW_RD0, W_WGT+OW_ML1, W_WGT+OW_ML2};
    const int    pn[21]   = {30000, 100000, 480000,
        640, 4096, 512, 4096, 16384, 16384, 40960, 192,
        4096, 512, 4096, 16384, 16384, 40960, 192, 64, 1024, 16};
    for (int i = 0; i < 21; i++){
        pa.s[i] = d_in[pidx[i]];
        pa.d[i] = fw + pdst[i];
        pa.n[i] = pn[i];
    }

    const int fastF32  = (ws_size >= NEED_F32);
    const int fastBF16 = (!fastF32 && ws_size >= NEED_BF16);

    hipMemsetAsync(iw + W_CNT, 0, NN * sizeof(int), stream);
    k_detect<<<1, 256, 0, stream>>>((const uint32_t*)d_in[1], iw + W_FLAG);
    k_prep<<<120, 256, 0, stream>>>(pa, iw + W_FLAG);
    if (fastF32 || fastBF16)
        k_wprep<<<2, 256, 0, stream>>>(fw + W_WGT, fw + W_WGT);
    k_geom<<<NE/256, 256, 0, stream>>>(fw + W_POS, fw + W_SHF, snd, rcv, fw + W_BES);
    k_hist<<<NE/256, 256, 0, stream>>>(rcv, iw + W_CNT);
    k_scan<<<1, 1024, 0, stream>>>(iw + W_CNT, iw + W_OFFS, iw + W_CUR);
    k_scatter<<<NE/256, 256, 0, stream>>>(rcv, snd, iw + W_CUR, iw + W_ORD, iw + W_SSND);
    k_embed<<<NN/4, 256, 0, stream>>>(fw + W_ATT, fw + W_WGT + OW_EMB, fw + W_NF0);

    // ---- interaction 0 ----
    k_h<<<NN/4, 256, 0, stream>>>(fw + W_NF0, fw + W_WGT + OW_UP0, fw + W_H);
    if (fastF32){
        k_mlp<1><<<NE/256, 256, 0, stream>>>(iw+W_ORD, fw+W_BES, fw+W_WGT+OW_W1T0,
                                             fw+W_WGT+OW_W2T0, fw+W_WGT+OW_W3T0, fw + W_R);
        k_gather<1><<<NN/4, 256, 0, stream>>>(iw+W_OFFS, iw+W_SSND, fw+W_H, fw + W_R, fw + W_A);
    } else if (fastBF16){
        k_mlp<0><<<NE/256, 256, 0, stream>>>(iw+W_ORD, fw+W_BES, fw+W_WGT+OW_W1T0,
                                             fw+W_WGT+OW_W2T0, fw+W_WGT+OW_W3T0, fw + W_R);
        k_gather<0><<<NN/4, 256, 0, stream>>>(iw+W_OFFS, iw+W_SSND, fw+W_H, fw + W_R, fw + W_A);
    } else {
        k_msg_fused<<<NN/4, 256, 0, stream>>>(iw+W_OFFS, iw+W_ORD, snd, fw+W_H, fw+W_BES,
                                              fw+W_WGT+OW_R10, fw+W_WGT+OW_R20,
                                              fw+W_WGT+OW_R30, fw + W_A);
    }
    k_node<0><<<NN/4, 256, 0, stream>>>(fw + W_A, fw + W_NF0, fw + W_ATT,
                                        fw + W_WGT + OW_MIX0, fw + W_WGT + OW_SC0,
                                        fw + W_WGT + OW_PR0, fw + W_WGT + OW_RD0, nullptr,
                                        fw + W_NF1, d_out, iw + W_FLAG);

    // ---- interaction 1 ----
    k_h<<<NN/4, 256, 0, stream>>>(fw + W_NF1, fw + W_WGT + OW_UP1, fw + W_H);
    if (fastF32){
        k_mlp<1><<<NE/256, 256, 0, stream>>>(iw+W_ORD, fw+W_BES, fw+W_WGT+OW_W1T1,
                                             fw+W_WGT+OW_W2T1, fw+W_WGT+OW_W3T1, fw + W_R);
        k_gather<1><<<NN/4, 256, 0, stream>>>(iw+W_OFFS, iw+W_SSND, fw+W_H, fw + W_R, fw + W_A);
    } else if (fastBF16){
        k_mlp<0><<<NE/256, 256, 0, stream>>>(iw+W_ORD, fw+W_BES, fw+W_WGT+OW_W1T1,
                                             fw+W_WGT+OW_W2T1, fw+W_WGT+OW_W3T1, fw + W_R);
        k_gather<0><<<NN/4, 256, 0, stream>>>(iw+W_OFFS, iw+W_SSND, fw+W_H, fw + W_R, fw + W_A);
    } else {
        k_msg_fused<<<NN/4, 256, 0, stream>>>(iw+W_OFFS, iw+W_ORD, snd, fw+W_H, fw+W_BES,
                                              fw+W_WGT+OW_R11, fw+W_WGT+OW_R21,
                                              fw+W_WGT+OW_R31, fw + W_A);
    }
    k_node<1><<<NN/4, 256, 0, stream>>>(fw + W_A, fw + W_NF1, fw + W_ATT,
                                        fw + W_WGT + OW_MIX1, fw + W_WGT + OW_SC1,
                                        fw + W_WGT + OW_PR1, fw + W_WGT + OW_ML1,
                                        fw + W_WGT + OW_ML2,
                                        nullptr, d_out, iw + W_FLAG);
}

// Round 7
// 510.409 us; speedup vs baseline: 2.4007x; 2.4007x over previous
//
#include <hip/hip_runtime.h>
#include <hip/hip_bf16.h>
#include <cstdint>
#include <cstddef>

#define NN 10000
#define NE 160000

typedef unsigned short u16;

__device__ __forceinline__ float b2f(u16 u){
    union { uint32_t i; float f; } v; v.i = ((uint32_t)u) << 16; return v.f;
}
__device__ __forceinline__ u16 f2b(float f){
    union { __hip_bfloat16 h; u16 u; } c; c.h = __float2bfloat16(f); return c.u;
}
__device__ __forceinline__ float silu_f(float x){ return x / (1.f + __expf(-x)); }

// ---------------- workspace layout (4-byte word offsets) ----------------
constexpr size_t W_FLAG = 0;                        // 16
constexpr size_t W_CNT  = 16;                       // 10000
constexpr size_t W_OFFS = 10016;                    // 10001
constexpr size_t W_CUR  = 20032;                    // 10000
constexpr size_t W_ORD  = 30032;                    // 160000
constexpr size_t W_SSND = 190032;                   // 160000
constexpr size_t W_ATT  = 350032;                   // 100000
constexpr size_t W_POS  = 450032;                   // 30000
constexpr size_t W_SHF  = 480032;                   // 480000
constexpr size_t W_WGT  = 960032;
constexpr size_t OW_EMB = 0;
constexpr size_t OW_UP0 = 640;
constexpr size_t OW_R10 = 4736;
constexpr size_t OW_R20 = 5248;
constexpr size_t OW_R30 = 9344;
constexpr size_t OW_MIX0= 25728;
constexpr size_t OW_SC0 = 42112;
constexpr size_t OW_PR0 = 83072;
constexpr size_t OW_UP1 = 83264;
constexpr size_t OW_R11 = 87360;
constexpr size_t OW_R21 = 87872;
constexpr size_t OW_R31 = 91968;
constexpr size_t OW_MIX1= 108352;
constexpr size_t OW_SC1 = 124736;
constexpr size_t OW_PR1 = 165696;
constexpr size_t OW_RD0 = 165888;
constexpr size_t OW_ML1 = 165952;
constexpr size_t OW_ML2 = 166976;
constexpr size_t OW_TEND = 167000;
constexpr size_t W_BES  = W_WGT + OW_TEND;          // [E,8] f32
constexpr size_t W_NF0  = W_BES + (size_t)NE*8;     // [N,64]
constexpr size_t W_H    = W_NF0 + (size_t)NN*64;
constexpr size_t W_A    = W_H   + (size_t)NN*64;
constexpr size_t W_NF1  = W_A   + (size_t)NN*64;
constexpr size_t W_R    = W_NF1 + (size_t)NN*64;    // R buffer (tiered), RECEIVER-SORTED

constexpr size_t NEED_BF16 = (W_R + (size_t)NE*32) * 4;  // ~40 MB
constexpr size_t NEED_F32  = (W_R + (size_t)NE*64) * 4;  // ~61 MB

// ---------------- dtype detection via exact one-hot structure of attrs ----------------
__global__ void k_detect(const uint32_t* __restrict__ attrs, int* __restrict__ flag){
    __shared__ int cnt_s;
    if (threadIdx.x == 0) cnt_s = 0;
    __syncthreads();
    int c = 0;
    for (int i = threadIdx.x; i < 50000; i += 256){
        uint32_t v = attrs[i];
        if (v != 0u && v != 0x3F800000u) c++;
    }
    atomicAdd(&cnt_s, c);
    __syncthreads();
    if (threadIdx.x == 0) flag[0] = (cnt_s > 100) ? 1 : 0;   // 1 = inputs are bf16
}

// ---------------- convert all float inputs -> fp32 workspace ----------------
struct PrepArgs { const void* s[21]; float* d[21]; int n[21]; };
__global__ void k_prep(PrepArgs a, const int* __restrict__ flag){
    int bf = flag[0];
    int stride = gridDim.x * blockDim.x;
    int t0 = blockIdx.x * blockDim.x + threadIdx.x;
    for (int k = 0; k < 21; k++){
        float* d = a.d[k]; int n = a.n[k];
        if (bf){
            const u16* s = (const u16*)a.s[k];
            for (int i = t0; i < n; i += stride) d[i] = b2f(s[i]);
        } else {
            const float* s = (const float*)a.s[k];
            for (int i = t0; i < n; i += stride) d[i] = s[i];
        }
    }
}

// ---------------- edge bessel features ----------------
__global__ void k_geom(const float* __restrict__ pos, const float* __restrict__ shf,
                       const int* __restrict__ snd, const int* __restrict__ rcv,
                       float* __restrict__ bess){
    int e = blockIdx.x * 256 + threadIdx.x;
    if (e >= NE) return;
    int s = snd[e], r = rcv[e];
    float vx = pos[r*3+0] - pos[s*3+0] + shf[e*3+0];
    float vy = pos[r*3+1] - pos[s*3+1] + shf[e*3+1];
    float vz = pos[r*3+2] - pos[s*3+2] + shf[e*3+2];
    float rr = sqrtf(vx*vx + vy*vy + vz*vz);
    float xr = rr * 0.1f;
    float x2 = xr*xr; float x5 = x2*x2*xr;
    float env = 1.f - 21.f*x5 + 35.f*x5*xr - 15.f*x5*x2;
    if (xr >= 1.f) env = 0.f;
    float scl = 0.4472135954999579f * env / (rr + 1e-9f);
    float* be = bess + (size_t)e*8;
    #pragma unroll
    for (int n = 1; n <= 8; n++)
        be[n-1] = scl * sinf((float)n * 3.14159265358979323846f * rr * 0.1f);
}

// ---------------- CSR build ----------------
__global__ void k_hist(const int* __restrict__ rcv, int* __restrict__ cnt){
    int e = blockIdx.x * 256 + threadIdx.x;
    if (e < NE) atomicAdd(&cnt[rcv[e]], 1);
}
__global__ void k_scan(const int* __restrict__ cnt, int* __restrict__ offs, int* __restrict__ cur){
    __shared__ int part[1024];
    int t = threadIdx.x;
    int base = t * 10;
    int s = 0;
    for (int i = 0; i < 10; i++) if (base + i < NN) s += cnt[base + i];
    part[t] = s; __syncthreads();
    for (int d = 1; d < 1024; d <<= 1){
        int v = part[t];
        if (t >= d) v += part[t - d];
        __syncthreads();
        part[t] = v;
        __syncthreads();
    }
    int run = part[t] - s;
    for (int i = 0; i < 10; i++){
        int idx = base + i;
        if (idx < NN){ offs[idx] = run; cur[idx] = run; run += cnt[idx]; }
    }
    if (t == 1023) offs[NN] = part[1023];
}
__global__ void k_scatter(const int* __restrict__ rcv, const int* __restrict__ snd,
                          int* __restrict__ cur, int* __restrict__ order, int* __restrict__ ssnd){
    int e = blockIdx.x * 256 + threadIdx.x;
    if (e < NE){
        int p = atomicAdd(&cur[rcv[e]], 1);
        order[p] = e;
        ssnd[p]  = snd[e];
    }
}

// ---------------- nf0 = attrs @ w_embed ----------------
__global__ void k_embed(const float* __restrict__ attrs, const float* __restrict__ Wemb,
                        float* __restrict__ nf0){
    int t = blockIdx.x * 256 + threadIdx.x;
    int n = t >> 6;
    int l = t & 63;
    float acc = 0.f;
    #pragma unroll
    for (int s = 0; s < 10; s++) acc += attrs[n*10 + s] * Wemb[s*64 + l];
    nf0[n*64 + l] = acc;
}

// ---------------- h = nf(:,:,0) @ W_up ----------------
__global__ void k_h(const float* __restrict__ src, const float* __restrict__ W,
                    float* __restrict__ h){
    int t = blockIdx.x * 256 + threadIdx.x;
    int n = t >> 6;
    int l = t & 63;
    const float* row = src + (size_t)n*64;
    float acc = 0.f;
    #pragma unroll 8
    for (int g = 0; g < 64; g++) acc += row[g] * W[g*64 + l];
    h[n*64 + l] = acc;
}

// ---------------- cooperative radial MLP: wave = 64 edges, lane = feature ----------------
// Weight columns in registers (loaded once); h1/h2 staged via per-wave LDS tile;
// inter-layer reads are same-address broadcasts; stores coalesced per edge row.
template<int RF32>
__global__ __launch_bounds__(128, 3) void k_mlp(const int* __restrict__ order,
        const float* __restrict__ bess,
        const float* __restrict__ W1, const float* __restrict__ W2,
        const float* __restrict__ W3, void* __restrict__ Rout){
    __shared__ float lds[2][16][64];
    int wv = threadIdx.x >> 6;
    int l  = threadIdx.x & 63;
    float w1c[8];
    #pragma unroll
    for (int i = 0; i < 8; i++) w1c[i] = W1[i*64 + l];
    float w2c[64];
    #pragma unroll
    for (int j = 0; j < 64; j++) w2c[j] = W2[j*64 + l];
    float w3c[64];
    #pragma unroll
    for (int j = 0; j < 64; j++) w3c[j] = W3[j*256 + 4*l];   // l'=0 slot of feature l
    int pwave = blockIdx.x * 128 + wv * 64;                  // 1250*128 == NE exact
    #pragma unroll 1
    for (int sb = 0; sb < 4; sb++){
        int pbase = pwave + sb * 16;
        // layer 1: h1[e][l]
        #pragma unroll
        for (int i = 0; i < 16; i++){
            int e = order[pbase + i];
            const float* be = bess + (size_t)e*8;
            float a = be[0]*w1c[0] + be[1]*w1c[1] + be[2]*w1c[2] + be[3]*w1c[3]
                    + be[4]*w1c[4] + be[5]*w1c[5] + be[6]*w1c[6] + be[7]*w1c[7];
            lds[wv][i][l] = silu_f(a);
        }
        // layer 2: h2[e][l] (reads row e broadcast, overwrites row e — in-wave lockstep safe)
        #pragma unroll
        for (int i = 0; i < 16; i++){
            float a0=0.f, a1=0.f, a2=0.f, a3=0.f;
            #pragma unroll
            for (int j = 0; j < 64; j += 4){
                float4 v = *(const float4*)&lds[wv][i][j];
                a0 += v.x * w2c[j+0];
                a1 += v.y * w2c[j+1];
                a2 += v.z * w2c[j+2];
                a3 += v.w * w2c[j+3];
            }
            lds[wv][i][l] = silu_f((a0+a1) + (a2+a3));
        }
        // layer 3: R[p][l], coalesced per-edge store
        #pragma unroll
        for (int i = 0; i < 16; i++){
            float a0=0.f, a1=0.f, a2=0.f, a3=0.f;
            #pragma unroll
            for (int j = 0; j < 64; j += 4){
                float4 v = *(const float4*)&lds[wv][i][j];
                a0 += v.x * w3c[j+0];
                a1 += v.y * w3c[j+1];
                a2 += v.z * w3c[j+2];
                a3 += v.w * w3c[j+3];
            }
            float r = (a0+a1) + (a2+a3);
            size_t p = (size_t)(pbase + i);
            if (RF32) ((float*)Rout)[p*64 + l] = r;
            else      ((u16*)Rout)[p*64 + l] = f2b(r);
        }
    }
}

// ---------------- CSR gather-sum: A[n,f] = (1/16) sum_p h[ssnd[p],f] * R[p,f] ----------------
template<int RF32>
__global__ __launch_bounds__(256) void k_gather(const int* __restrict__ offs,
        const int* __restrict__ ssnd, const float* __restrict__ h,
        const void* __restrict__ R, float* __restrict__ A){
    int wv = threadIdx.x >> 6;
    int n  = blockIdx.x * 4 + wv;
    int l  = threadIdx.x & 63;
    int beg = __builtin_amdgcn_readfirstlane(offs[n]);
    int end = __builtin_amdgcn_readfirstlane(offs[n+1]);
    float acc = 0.f;
    int p = beg;
    for (; p + 4 <= end; p += 4){
        int s0 = __builtin_amdgcn_readfirstlane(ssnd[p+0]);
        int s1 = __builtin_amdgcn_readfirstlane(ssnd[p+1]);
        int s2 = __builtin_amdgcn_readfirstlane(ssnd[p+2]);
        int s3 = __builtin_amdgcn_readfirstlane(ssnd[p+3]);
        float r0, r1, r2, r3;
        if (RF32){
            const float* Rf = (const float*)R;
            r0 = Rf[(size_t)(p+0)*64 + l];
            r1 = Rf[(size_t)(p+1)*64 + l];
            r2 = Rf[(size_t)(p+2)*64 + l];
            r3 = Rf[(size_t)(p+3)*64 + l];
        } else {
            const u16* Rb = (const u16*)R;
            r0 = b2f(Rb[(size_t)(p+0)*64 + l]);
            r1 = b2f(Rb[(size_t)(p+1)*64 + l]);
            r2 = b2f(Rb[(size_t)(p+2)*64 + l]);
            r3 = b2f(Rb[(size_t)(p+3)*64 + l]);
        }
        float h0v = h[s0*64 + l];
        float h1v = h[s1*64 + l];
        float h2v = h[s2*64 + l];
        float h3v = h[s3*64 + l];
        acc += h0v*r0 + h1v*r1 + h2v*r2 + h3v*r3;
    }
    for (; p < end; p++){
        int s = __builtin_amdgcn_readfirstlane(ssnd[p]);
        float rv;
        if (RF32) rv = ((const float*)R)[(size_t)p*64 + l];
        else      rv = b2f(((const u16*)R)[(size_t)p*64 + l]);
        acc += h[s*64 + l] * rv;
    }
    A[n*64 + l] = acc * 0.0625f;
}

// ---------------- legacy fused msg (fallback when ws too small for R buffer) ----------------
__global__ __launch_bounds__(256) void k_msg_fused(const int* __restrict__ offs, const int* __restrict__ order,
        const int* __restrict__ snd, const float* __restrict__ h, const float* __restrict__ bess,
        const float* __restrict__ W1, const float* __restrict__ W2, const float* __restrict__ W3,
        float* __restrict__ A){
    int wv = threadIdx.x >> 6;
    int n  = blockIdx.x * 4 + wv;
    int l  = threadIdx.x & 63;
    float w1c[8];
    #pragma unroll
    for (int i = 0; i < 8; i++) w1c[i] = W1[i*64 + l];
    float w2c[64];
    #pragma unroll
    for (int j = 0; j < 64; j++) w2c[j] = W2[j*64 + l];
    float w3c[64];
    #pragma unroll
    for (int j = 0; j < 64; j++) w3c[j] = W3[j*256 + 4*l];
    float acc = 0.f;
    int beg = __builtin_amdgcn_readfirstlane(offs[n]);
    int end = __builtin_amdgcn_readfirstlane(offs[n+1]);
    for (int p = beg; p < end; p++){
        int e = __builtin_amdgcn_readfirstlane(order[p]);
        int s = __builtin_amdgcn_readfirstlane(snd[e]);
        const float* be = bess + (size_t)e*8;
        float h1 = 0.f;
        #pragma unroll
        for (int i = 0; i < 8; i++) h1 += be[i] * w1c[i];
        h1 = silu_f(h1);
        float h2 = 0.f;
        #pragma unroll
        for (int j = 0; j < 64; j++) h2 += __shfl(h1, j) * w2c[j];
        h2 = silu_f(h2);
        float r = 0.f;
        #pragma unroll
        for (int j = 0; j < 64; j++) r += __shfl(h2, j) * w3c[j];
        acc += h[s*64 + l] * r;
    }
    A[n*64 + l] = acc * 0.0625f;
}

// ---------------- node update (mix k=0 + sc + poly) + readout ----------------
template<int LAST>
__global__ __launch_bounds__(256) void k_node(const float* __restrict__ A, const float* __restrict__ nf,
        const float* __restrict__ attrs, const float* __restrict__ Wmix0, const float* __restrict__ Wsc,
        const float* __restrict__ Wprod, const float* __restrict__ Wtail, const float* __restrict__ Wml2,
        float* __restrict__ nf1out, void* __restrict__ out, const int* __restrict__ flag){
    int wv = threadIdx.x >> 6;
    int n  = blockIdx.x * 4 + wv;
    int l  = threadIdx.x & 63;
    float Af  = A[n*64 + l];
    float nff = nf[n*64 + l];
    float am = 0.f;
    #pragma unroll 16
    for (int f = 0; f < 64; f++) am += __shfl(Af, f) * Wmix0[f*64 + l];
    float sc = 0.f;
    for (int s = 0; s < 10; s++){
        float av = attrs[n*10 + s];       // wave-uniform
        if (av != 0.f){
            const float* Ws = Wsc + s*4096;
            float t = 0.f;
            #pragma unroll 16
            for (int f = 0; f < 64; f++) t += __shfl(nff, f) * Ws[f*64 + l];
            sc += av * t;
        }
    }
    float poly = Wprod[l] + Wprod[64 + l]*am + Wprod[128 + l]*am*am;
    float val = am*poly + sc;
    float rv;
    if (LAST == 0){
        nf1out[n*64 + l] = val;
        rv = val * Wtail[l];
    } else {
        // all 64 lanes run the shfl loop (shfl under divergence is UB on CDNA)
        int lj = l & 15;
        float t = 0.f;
        #pragma unroll 16
        for (int g = 0; g < 64; g++){
            float vg = __shfl(val, g);
            t += vg * Wtail[g*16 + lj];
        }
        rv = (l < 16) ? (silu_f(t) * Wml2[lj]) : 0.f;
    }
    #pragma unroll
    for (int o2 = 32; o2; o2 >>= 1) rv += __shfl_down(rv, o2);
    if (l == 0){
        int idx = 2*n + LAST;
        if (flag[0]) ((__hip_bfloat16*)out)[idx] = __float2bfloat16(rv);
        else         ((float*)out)[idx] = rv;
    }
}

// ---------------- launch ----------------
extern "C" void kernel_launch(void* const* d_in, const int* in_sizes, int n_in,
                              void* d_out, int out_size, void* d_ws, size_t ws_size,
                              hipStream_t stream) {
    int*   iw = (int*)d_ws;
    float* fw = (float*)d_ws;
    const int* snd = (const int*)d_in[3];
    const int* rcv = (const int*)d_in[4];

    PrepArgs pa;
    const int    pidx[21] = {0,1,2, 5,6,7,8,9,10,11,12,13,14,15,16,17,18,19,20,21,22};
    const size_t pdst[21] = {W_POS, W_ATT, W_SHF,
        W_WGT+OW_EMB, W_WGT+OW_UP0, W_WGT+OW_R10, W_WGT+OW_R20, W_WGT+OW_R30,
        W_WGT+OW_MIX0, W_WGT+OW_SC0, W_WGT+OW_PR0,
        W_WGT+OW_UP1, W_WGT+OW_R11, W_WGT+OW_R21, W_WGT+OW_R31,
        W_WGT+OW_MIX1, W_WGT+OW_SC1, W_WGT+OW_PR1,
        W_WGT+OW_RD0, W_WGT+OW_ML1, W_WGT+OW_ML2};
    const int    pn[21]   = {30000, 100000, 480000,
        640, 4096, 512, 4096, 16384, 16384, 40960, 192,
        4096, 512, 4096, 16384, 16384, 40960, 192, 64, 1024, 16};
    for (int i = 0; i < 21; i++){
        pa.s[i] = d_in[pidx[i]];
        pa.d[i] = fw + pdst[i];
        pa.n[i] = pn[i];
    }

    const int fastF32  = (ws_size >= NEED_F32);
    const int fastBF16 = (!fastF32 && ws_size >= NEED_BF16);

    hipMemsetAsync(iw + W_CNT, 0, NN * sizeof(int), stream);
    k_detect<<<1, 256, 0, stream>>>((const uint32_t*)d_in[1], iw + W_FLAG);
    k_prep<<<120, 256, 0, stream>>>(pa, iw + W_FLAG);
    k_geom<<<NE/256, 256, 0, stream>>>(fw + W_POS, fw + W_SHF, snd, rcv, fw + W_BES);
    k_hist<<<NE/256, 256, 0, stream>>>(rcv, iw + W_CNT);
    k_scan<<<1, 1024, 0, stream>>>(iw + W_CNT, iw + W_OFFS, iw + W_CUR);
    k_scatter<<<NE/256, 256, 0, stream>>>(rcv, snd, iw + W_CUR, iw + W_ORD, iw + W_SSND);
    k_embed<<<NN/4, 256, 0, stream>>>(fw + W_ATT, fw + W_WGT + OW_EMB, fw + W_NF0);

    // ---- interaction 0 ----
    k_h<<<NN/4, 256, 0, stream>>>(fw + W_NF0, fw + W_WGT + OW_UP0, fw + W_H);
    if (fastF32){
        k_mlp<1><<<NE/128, 128, 0, stream>>>(iw+W_ORD, fw+W_BES, fw+W_WGT+OW_R10,
                                             fw+W_WGT+OW_R20, fw+W_WGT+OW_R30, fw + W_R);
        k_gather<1><<<NN/4, 256, 0, stream>>>(iw+W_OFFS, iw+W_SSND, fw+W_H, fw + W_R, fw + W_A);
    } else if (fastBF16){
        k_mlp<0><<<NE/128, 128, 0, stream>>>(iw+W_ORD, fw+W_BES, fw+W_WGT+OW_R10,
                                             fw+W_WGT+OW_R20, fw+W_WGT+OW_R30, fw + W_R);
        k_gather<0><<<NN/4, 256, 0, stream>>>(iw+W_OFFS, iw+W_SSND, fw+W_H, fw + W_R, fw + W_A);
    } else {
        k_msg_fused<<<NN/4, 256, 0, stream>>>(iw+W_OFFS, iw+W_ORD, snd, fw+W_H, fw+W_BES,
                                              fw+W_WGT+OW_R10, fw+W_WGT+OW_R20,
                                              fw+W_WGT+OW_R30, fw + W_A);
    }
    k_node<0><<<NN/4, 256, 0, stream>>>(fw + W_A, fw + W_NF0, fw + W_ATT,
                                        fw + W_WGT + OW_MIX0, fw + W_WGT + OW_SC0,
                                        fw + W_WGT + OW_PR0, fw + W_WGT + OW_RD0, nullptr,
                                        fw + W_NF1, d_out, iw + W_FLAG);

    // ---- interaction 1 ----
    k_h<<<NN/4, 256, 0, stream>>>(fw + W_NF1, fw + W_WGT + OW_UP1, fw + W_H);
    if (fastF32){
        k_mlp<1><<<NE/128, 128, 0, stream>>>(iw+W_ORD, fw+W_BES, fw+W_WGT+OW_R11,
                                             fw+W_WGT+OW_R21, fw+W_WGT+OW_R31, fw + W_R);
        k_gather<1><<<NN/4, 256, 0, stream>>>(iw+W_OFFS, iw+W_SSND, fw+W_H, fw + W_R, fw + W_A);
    } else if (fastBF16){
        k_mlp<0><<<NE/128, 128, 0, stream>>>(iw+W_ORD, fw+W_BES, fw+W_WGT+OW_R11,
                                             fw+W_WGT+OW_R21, fw+W_WGT+OW_R31, fw + W_R);
        k_gather<0><<<NN/4, 256, 0, stream>>>(iw+W_OFFS, iw+W_SSND, fw+W_H, fw + W_R, fw + W_A);
    } else {
        k_msg_fused<<<NN/4, 256, 0, stream>>>(iw+W_OFFS, iw+W_ORD, snd, fw+W_H, fw+W_BES,
                                              fw+W_WGT+OW_R11, fw+W_WGT+OW_R21,
                                              fw+W_WGT+OW_R31, fw + W_A);
    }
    k_node<1><<<NN/4, 256, 0, stream>>>(fw + W_A, fw + W_NF1, fw + W_ATT,
                                        fw + W_WGT + OW_MIX1, fw + W_WGT + OW_SC1,
                                        fw + W_WGT + OW_PR1, fw + W_WGT + OW_ML1,
                                        fw + W_WGT + OW_ML2,
                                        nullptr, d_out, iw + W_FLAG);
}

// Round 8
// 334.612 us; speedup vs baseline: 3.6619x; 1.5254x over previous
//
#include <hip/hip_runtime.h>
#include <hip/hip_bf16.h>
#include <cstdint>
#include <cstddef>

#define NN 10000
#define NE 160000

typedef unsigned short u16;
typedef __attribute__((ext_vector_type(8))) short short8;
typedef __attribute__((ext_vector_type(4))) float f32x4;

__device__ __forceinline__ float b2f(u16 u){
    union { uint32_t i; float f; } v; v.i = ((uint32_t)u) << 16; return v.f;
}
__device__ __forceinline__ u16 f2b(float f){
    union { __hip_bfloat16 h; u16 u; } c; c.h = __float2bfloat16(f); return c.u;
}
__device__ __forceinline__ float silu_f(float x){ return x / (1.f + __expf(-x)); }

// ---------------- workspace layout (4-byte word offsets) ----------------
constexpr size_t W_FLAG = 0;                        // 16
constexpr size_t W_CNT  = 16;                       // 10000
constexpr size_t W_OFFS = 10016;                    // 10001
constexpr size_t W_CUR  = 20032;                    // 10000
constexpr size_t W_SSND = 30032;                    // 160000 (sender per sorted pos)
constexpr size_t W_INV  = 190032;                   // 160000 (edge -> sorted pos)
constexpr size_t W_ATT  = 350032;                   // 100000
constexpr size_t W_POS  = 450032;                   // 30000
constexpr size_t W_SHF  = 480032;                   // 480000
constexpr size_t W_WGT  = 960032;
constexpr size_t OW_EMB = 0;
constexpr size_t OW_UP0 = 640;
constexpr size_t OW_R10 = 4736;
constexpr size_t OW_R20 = 5248;
constexpr size_t OW_R30 = 9344;
constexpr size_t OW_MIX0= 25728;
constexpr size_t OW_SC0 = 42112;
constexpr size_t OW_PR0 = 83072;
constexpr size_t OW_UP1 = 83264;
constexpr size_t OW_R11 = 87360;
constexpr size_t OW_R21 = 87872;
constexpr size_t OW_R31 = 91968;
constexpr size_t OW_MIX1= 108352;
constexpr size_t OW_SC1 = 124736;
constexpr size_t OW_PR1 = 165696;
constexpr size_t OW_RD0 = 165888;
constexpr size_t OW_ML1 = 165952;
constexpr size_t OW_ML2 = 166976;
constexpr size_t OW_TEND = 167000;
constexpr size_t W_BES  = W_WGT + OW_TEND;          // [E][8] f32, RECEIVER-SORTED
constexpr size_t W_NF0  = W_BES + (size_t)NE*8;     // [N,64]
constexpr size_t W_H    = W_NF0 + (size_t)NN*64;
constexpr size_t W_A    = W_H   + (size_t)NN*64;
constexpr size_t W_NF1  = W_A   + (size_t)NN*64;
constexpr size_t W_R    = W_NF1 + (size_t)NN*64;    // [E][64] bf16, RECEIVER-SORTED

constexpr size_t NEED_BF16 = (W_R + (size_t)NE*32) * 4;  // ~40.4 MB

// ---------------- dtype detection via exact one-hot structure of attrs ----------------
__global__ void k_detect(const uint32_t* __restrict__ attrs, int* __restrict__ flag){
    __shared__ int cnt_s;
    if (threadIdx.x == 0) cnt_s = 0;
    __syncthreads();
    int c = 0;
    for (int i = threadIdx.x; i < 50000; i += 256){
        uint32_t v = attrs[i];
        if (v != 0u && v != 0x3F800000u) c++;
    }
    atomicAdd(&cnt_s, c);
    __syncthreads();
    if (threadIdx.x == 0) flag[0] = (cnt_s > 100) ? 1 : 0;   // 1 = inputs are bf16
}

// ---------------- convert all float inputs -> fp32 workspace ----------------
struct PrepArgs { const void* s[21]; float* d[21]; int n[21]; };
__global__ void k_prep(PrepArgs a, const int* __restrict__ flag){
    int bf = flag[0];
    int stride = gridDim.x * blockDim.x;
    int t0 = blockIdx.x * blockDim.x + threadIdx.x;
    for (int k = 0; k < 21; k++){
        float* d = a.d[k]; int n = a.n[k];
        if (bf){
            const u16* s = (const u16*)a.s[k];
            for (int i = t0; i < n; i += stride) d[i] = b2f(s[i]);
        } else {
            const float* s = (const float*)a.s[k];
            for (int i = t0; i < n; i += stride) d[i] = s[i];
        }
    }
}

// ---------------- CSR build ----------------
__global__ void k_hist(const int* __restrict__ rcv, int* __restrict__ cnt){
    int e = blockIdx.x * 256 + threadIdx.x;
    if (e < NE) atomicAdd(&cnt[rcv[e]], 1);
}
__global__ void k_scan(const int* __restrict__ cnt, int* __restrict__ offs, int* __restrict__ cur){
    __shared__ int part[1024];
    int t = threadIdx.x;
    int base = t * 10;
    int s = 0;
    for (int i = 0; i < 10; i++) if (base + i < NN) s += cnt[base + i];
    part[t] = s; __syncthreads();
    for (int d = 1; d < 1024; d <<= 1){
        int v = part[t];
        if (t >= d) v += part[t - d];
        __syncthreads();
        part[t] = v;
        __syncthreads();
    }
    int run = part[t] - s;
    for (int i = 0; i < 10; i++){
        int idx = base + i;
        if (idx < NN){ offs[idx] = run; cur[idx] = run; run += cnt[idx]; }
    }
    if (t == 1023) offs[NN] = part[1023];
}
__global__ void k_scatter(const int* __restrict__ rcv, const int* __restrict__ snd,
                          int* __restrict__ cur, int* __restrict__ ssnd, int* __restrict__ inv){
    int e = blockIdx.x * 256 + threadIdx.x;
    if (e < NE){
        int p = atomicAdd(&cur[rcv[e]], 1);
        ssnd[p] = snd[e];
        inv[e]  = p;
    }
}

// ---------------- edge bessel features, written RECEIVER-SORTED ----------------
__global__ void k_geom(const float* __restrict__ pos, const float* __restrict__ shf,
                       const int* __restrict__ snd, const int* __restrict__ rcv,
                       const int* __restrict__ inv, float* __restrict__ bessp){
    int e = blockIdx.x * 256 + threadIdx.x;
    if (e >= NE) return;
    int s = snd[e], r = rcv[e];
    float vx = pos[r*3+0] - pos[s*3+0] + shf[e*3+0];
    float vy = pos[r*3+1] - pos[s*3+1] + shf[e*3+1];
    float vz = pos[r*3+2] - pos[s*3+2] + shf[e*3+2];
    float rr = sqrtf(vx*vx + vy*vy + vz*vz);
    float xr = rr * 0.1f;
    float x2 = xr*xr; float x5 = x2*x2*xr;
    float env = 1.f - 21.f*x5 + 35.f*x5*xr - 15.f*x5*x2;
    if (xr >= 1.f) env = 0.f;
    float scl = 0.4472135954999579f * env / (rr + 1e-9f);
    float* be = bessp + (size_t)inv[e]*8;
    #pragma unroll
    for (int n = 1; n <= 8; n++)
        be[n-1] = scl * sinf((float)n * 3.14159265358979323846f * rr * 0.1f);
}

// ---------------- nf0 = attrs @ w_embed ----------------
__global__ void k_embed(const float* __restrict__ attrs, const float* __restrict__ Wemb,
                        float* __restrict__ nf0){
    int t = blockIdx.x * 256 + threadIdx.x;
    int n = t >> 6;
    int l = t & 63;
    float acc = 0.f;
    #pragma unroll
    for (int s = 0; s < 10; s++) acc += attrs[n*10 + s] * Wemb[s*64 + l];
    nf0[n*64 + l] = acc;
}

// ---------------- h = nf(:,:,0) @ W_up ----------------
__global__ void k_h(const float* __restrict__ src, const float* __restrict__ W,
                    float* __restrict__ h){
    int t = blockIdx.x * 256 + threadIdx.x;
    int n = t >> 6;
    int l = t & 63;
    const float* row = src + (size_t)n*64;
    float acc = 0.f;
    #pragma unroll 8
    for (int g = 0; g < 64; g++) acc += row[g] * W[g*64 + l];
    h[n*64 + l] = acc;
}

// ---------------- MFMA radial MLP: block = 64 edges, bf16 matrix cores ----------------
// LDS fragment layouts: activations [k-octet][edge][8], weights [k-octet][n][8];
// every MFMA operand read is a stride-1 ds_read_b128 (1 KB unique data per instr).
constexpr int OCT = 520;   // u16 per octet block (512 + 8 pad -> byte stride 1040, 16B aligned)

__global__ __launch_bounds__(256) void k_mlp_mfma(const float* __restrict__ bessp,
        const float* __restrict__ W1, const float* __restrict__ W2,
        const float* __restrict__ W3, u16* __restrict__ R){
    __shared__ u16 Xa[8*OCT];   // h1 tile
    __shared__ u16 Xb[8*OCT];   // h2 tile
    __shared__ u16 Wa[8*OCT];   // W2 B-frags
    __shared__ u16 Wb[8*OCT];   // W3 (l'=0 slice) B-frags
    __shared__ u16 Xc[4*OCT];   // bess A-frags (K=32, octs 1-3 zero)
    __shared__ u16 Wc[4*OCT];   // W1 B-frags (K=32, octs 1-3 zero)
    int t = threadIdx.x;
    int w = t >> 6, lane = t & 63;
    int q = lane >> 4, r = lane & 15;
    int pbase = blockIdx.x * 64;                 // 2500 * 64 == NE

    // zero the K-padded small buffers
    for (int i = t; i < 4*OCT/8; i += 256){
        ((short8*)Xc)[i] = (short8)0;
        ((short8*)Wc)[i] = (short8)0;
    }
    // W2 / W3 -> B-frag layout [oct][n][j]  (pairs of k packed as one u32 store)
    for (int i = t; i < 2048; i += 256){
        int k = (i >> 6) * 2, n = i & 63;
        uint32_t w2p = ((uint32_t)f2b(W2[(k+1)*64 + n]) << 16) | f2b(W2[k*64 + n]);
        uint32_t w3p = ((uint32_t)f2b(W3[(k+1)*256 + 4*n]) << 16) | f2b(W3[k*256 + 4*n]);
        *(uint32_t*)&Wa[(k>>3)*OCT + n*8 + (k&7)] = w2p;
        *(uint32_t*)&Wb[(k>>3)*OCT + n*8 + (k&7)] = w3p;
    }
    __syncthreads();   // Xc/Wc zeros visible before oct0 fill (avoid race on same rows)
    // W1 [8][64] -> Wc oct0 ([n][k])
    for (int i = t; i < 512; i += 256){
        int k = i >> 6, n = i & 63;
        Wc[n*8 + k] = f2b(W1[i]);
    }
    // bess (receiver-sorted, contiguous) -> Xc oct0 ([e][k])
    for (int i = t; i < 512; i += 256){
        Xc[i] = f2b(bessp[(size_t)pbase*8 + i]);
    }
    __syncthreads();

    int et = w;                                   // wave -> 16-edge tile
    int erow = et*16 + r;
    // ---- layer 1: K=8 (padded to 32), one MFMA per n-tile ----
    {
        short8 a = *(const short8*)&Xc[q*OCT + erow*8];
        #pragma unroll
        for (int nt = 0; nt < 4; nt++){
            short8 b = *(const short8*)&Wc[q*OCT + (nt*16 + r)*8];
            f32x4 c = {0.f, 0.f, 0.f, 0.f};
            c = __builtin_amdgcn_mfma_f32_16x16x32_bf16(a, b, c, 0, 0, 0);
            #pragma unroll
            for (int g = 0; g < 4; g++){
                int e = et*16 + q*4 + g;
                int n = nt*16 + r;
                Xa[(n>>3)*OCT + e*8 + (n&7)] = f2b(silu_f(c[g]));
            }
        }
    }
    __syncthreads();
    // ---- layer 2: K=64 (2 MFMAs) ----
    {
        short8 a0 = *(const short8*)&Xa[q*OCT + erow*8];
        short8 a1 = *(const short8*)&Xa[(4+q)*OCT + erow*8];
        #pragma unroll
        for (int nt = 0; nt < 4; nt++){
            short8 b0 = *(const short8*)&Wa[q*OCT + (nt*16 + r)*8];
            short8 b1 = *(const short8*)&Wa[(4+q)*OCT + (nt*16 + r)*8];
            f32x4 c = {0.f, 0.f, 0.f, 0.f};
            c = __builtin_amdgcn_mfma_f32_16x16x32_bf16(a0, b0, c, 0, 0, 0);
            c = __builtin_amdgcn_mfma_f32_16x16x32_bf16(a1, b1, c, 0, 0, 0);
            #pragma unroll
            for (int g = 0; g < 4; g++){
                int e = et*16 + q*4 + g;
                int n = nt*16 + r;
                Xb[(n>>3)*OCT + e*8 + (n&7)] = f2b(silu_f(c[g]));
            }
        }
    }
    __syncthreads();
    // ---- layer 3: K=64, no activation, store R (bf16, receiver-sorted) ----
    {
        short8 a0 = *(const short8*)&Xb[q*OCT + erow*8];
        short8 a1 = *(const short8*)&Xb[(4+q)*OCT + erow*8];
        #pragma unroll
        for (int nt = 0; nt < 4; nt++){
            short8 b0 = *(const short8*)&Wb[q*OCT + (nt*16 + r)*8];
            short8 b1 = *(const short8*)&Wb[(4+q)*OCT + (nt*16 + r)*8];
            f32x4 c = {0.f, 0.f, 0.f, 0.f};
            c = __builtin_amdgcn_mfma_f32_16x16x32_bf16(a0, b0, c, 0, 0, 0);
            c = __builtin_amdgcn_mfma_f32_16x16x32_bf16(a1, b1, c, 0, 0, 0);
            #pragma unroll
            for (int g = 0; g < 4; g++){
                int e = et*16 + q*4 + g;
                int n = nt*16 + r;
                R[(size_t)(pbase + e)*64 + n] = f2b(c[g]);
            }
        }
    }
}

// ---------------- CSR gather-sum: A[n,f] = (1/16) sum_p h[ssnd[p],f] * R[p,f] ----------------
__global__ __launch_bounds__(256) void k_gather(const int* __restrict__ offs,
        const int* __restrict__ ssnd, const float* __restrict__ h,
        const u16* __restrict__ R, float* __restrict__ A){
    int wv = threadIdx.x >> 6;
    int n  = blockIdx.x * 4 + wv;
    int l  = threadIdx.x & 63;
    int beg = __builtin_amdgcn_readfirstlane(offs[n]);
    int end = __builtin_amdgcn_readfirstlane(offs[n+1]);
    float acc = 0.f;
    int p = beg;
    for (; p + 4 <= end; p += 4){
        int s0 = __builtin_amdgcn_readfirstlane(ssnd[p+0]);
        int s1 = __builtin_amdgcn_readfirstlane(ssnd[p+1]);
        int s2 = __builtin_amdgcn_readfirstlane(ssnd[p+2]);
        int s3 = __builtin_amdgcn_readfirstlane(ssnd[p+3]);
        float r0 = b2f(R[(size_t)(p+0)*64 + l]);
        float r1 = b2f(R[(size_t)(p+1)*64 + l]);
        float r2 = b2f(R[(size_t)(p+2)*64 + l]);
        float r3 = b2f(R[(size_t)(p+3)*64 + l]);
        float h0v = h[s0*64 + l];
        float h1v = h[s1*64 + l];
        float h2v = h[s2*64 + l];
        float h3v = h[s3*64 + l];
        acc += h0v*r0 + h1v*r1 + h2v*r2 + h3v*r3;
    }
    for (; p < end; p++){
        int s = __builtin_amdgcn_readfirstlane(ssnd[p]);
        acc += h[s*64 + l] * b2f(R[(size_t)p*64 + l]);
    }
    A[n*64 + l] = acc * 0.0625f;
}

// ---------------- legacy fused msg (fallback when ws too small for R buffer) ----------------
__global__ __launch_bounds__(256) void k_msg_fused(const int* __restrict__ offs,
        const int* __restrict__ ssnd, const float* __restrict__ h, const float* __restrict__ bessp,
        const float* __restrict__ W1, const float* __restrict__ W2, const float* __restrict__ W3,
        float* __restrict__ A){
    int wv = threadIdx.x >> 6;
    int n  = blockIdx.x * 4 + wv;
    int l  = threadIdx.x & 63;
    float w1c[8];
    #pragma unroll
    for (int i = 0; i < 8; i++) w1c[i] = W1[i*64 + l];
    float w2c[64];
    #pragma unroll
    for (int j = 0; j < 64; j++) w2c[j] = W2[j*64 + l];
    float w3c[64];
    #pragma unroll
    for (int j = 0; j < 64; j++) w3c[j] = W3[j*256 + 4*l];
    float acc = 0.f;
    int beg = __builtin_amdgcn_readfirstlane(offs[n]);
    int end = __builtin_amdgcn_readfirstlane(offs[n+1]);
    for (int p = beg; p < end; p++){
        int s = __builtin_amdgcn_readfirstlane(ssnd[p]);
        const float* be = bessp + (size_t)p*8;
        float h1 = 0.f;
        #pragma unroll
        for (int i = 0; i < 8; i++) h1 += be[i] * w1c[i];
        h1 = silu_f(h1);
        float h2 = 0.f;
        #pragma unroll
        for (int j = 0; j < 64; j++) h2 += __shfl(h1, j) * w2c[j];
        h2 = silu_f(h2);
        float rr = 0.f;
        #pragma unroll
        for (int j = 0; j < 64; j++) rr += __shfl(h2, j) * w3c[j];
        acc += h[s*64 + l] * rr;
    }
    A[n*64 + l] = acc * 0.0625f;
}

// ---------------- node update (mix k=0 + sc + poly) + readout ----------------
template<int LAST>
__global__ __launch_bounds__(256) void k_node(const float* __restrict__ A, const float* __restrict__ nf,
        const float* __restrict__ attrs, const float* __restrict__ Wmix0, const float* __restrict__ Wsc,
        const float* __restrict__ Wprod, const float* __restrict__ Wtail, const float* __restrict__ Wml2,
        float* __restrict__ nf1out, void* __restrict__ out, const int* __restrict__ flag){
    int wv = threadIdx.x >> 6;
    int n  = blockIdx.x * 4 + wv;
    int l  = threadIdx.x & 63;
    float Af  = A[n*64 + l];
    float nff = nf[n*64 + l];
    float am = 0.f;
    #pragma unroll 16
    for (int f = 0; f < 64; f++) am += __shfl(Af, f) * Wmix0[f*64 + l];
    float sc = 0.f;
    for (int s = 0; s < 10; s++){
        float av = attrs[n*10 + s];       // wave-uniform
        if (av != 0.f){
            const float* Ws = Wsc + s*4096;
            float t = 0.f;
            #pragma unroll 16
            for (int f = 0; f < 64; f++) t += __shfl(nff, f) * Ws[f*64 + l];
            sc += av * t;
        }
    }
    float poly = Wprod[l] + Wprod[64 + l]*am + Wprod[128 + l]*am*am;
    float val = am*poly + sc;
    float rv;
    if (LAST == 0){
        nf1out[n*64 + l] = val;
        rv = val * Wtail[l];
    } else {
        // all 64 lanes run the shfl loop (shfl under divergence is UB on CDNA)
        int lj = l & 15;
        float t = 0.f;
        #pragma unroll 16
        for (int g = 0; g < 64; g++){
            float vg = __shfl(val, g);
            t += vg * Wtail[g*16 + lj];
        }
        rv = (l < 16) ? (silu_f(t) * Wml2[lj]) : 0.f;
    }
    #pragma unroll
    for (int o2 = 32; o2; o2 >>= 1) rv += __shfl_down(rv, o2);
    if (l == 0){
        int idx = 2*n + LAST;
        if (flag[0]) ((__hip_bfloat16*)out)[idx] = __float2bfloat16(rv);
        else         ((float*)out)[idx] = rv;
    }
}

// ---------------- launch ----------------
extern "C" void kernel_launch(void* const* d_in, const int* in_sizes, int n_in,
                              void* d_out, int out_size, void* d_ws, size_t ws_size,
                              hipStream_t stream) {
    int*   iw = (int*)d_ws;
    float* fw = (float*)d_ws;
    const int* snd = (const int*)d_in[3];
    const int* rcv = (const int*)d_in[4];

    PrepArgs pa;
    const int    pidx[21] = {0,1,2, 5,6,7,8,9,10,11,12,13,14,15,16,17,18,19,20,21,22};
    const size_t pdst[21] = {W_POS, W_ATT, W_SHF,
        W_WGT+OW_EMB, W_WGT+OW_UP0, W_WGT+OW_R10, W_WGT+OW_R20, W_WGT+OW_R30,
        W_WGT+OW_MIX0, W_WGT+OW_SC0, W_WGT+OW_PR0,
        W_WGT+OW_UP1, W_WGT+OW_R11, W_WGT+OW_R21, W_WGT+OW_R31,
        W_WGT+OW_MIX1, W_WGT+OW_SC1, W_WGT+OW_PR1,
        W_WGT+OW_RD0, W_WGT+OW_ML1, W_WGT+OW_ML2};
    const int    pn[21]   = {30000, 100000, 480000,
        640, 4096, 512, 4096, 16384, 16384, 40960, 192,
        4096, 512, 4096, 16384, 16384, 40960, 192, 64, 1024, 16};
    for (int i = 0; i < 21; i++){
        pa.s[i] = d_in[pidx[i]];
        pa.d[i] = fw + pdst[i];
        pa.n[i] = pn[i];
    }

    const int fast = (ws_size >= NEED_BF16);

    hipMemsetAsync(iw + W_CNT, 0, NN * sizeof(int), stream);
    k_detect<<<1, 256, 0, stream>>>((const uint32_t*)d_in[1], iw + W_FLAG);
    k_prep<<<120, 256, 0, stream>>>(pa, iw + W_FLAG);
    k_hist<<<NE/256, 256, 0, stream>>>(rcv, iw + W_CNT);
    k_scan<<<1, 1024, 0, stream>>>(iw + W_CNT, iw + W_OFFS, iw + W_CUR);
    k_scatter<<<NE/256, 256, 0, stream>>>(rcv, snd, iw + W_CUR, iw + W_SSND, iw + W_INV);
    k_geom<<<NE/256, 256, 0, stream>>>(fw + W_POS, fw + W_SHF, snd, rcv, iw + W_INV, fw + W_BES);
    k_embed<<<NN/4, 256, 0, stream>>>(fw + W_ATT, fw + W_WGT + OW_EMB, fw + W_NF0);

    // ---- interaction 0 ----
    k_h<<<NN/4, 256, 0, stream>>>(fw + W_NF0, fw + W_WGT + OW_UP0, fw + W_H);
    if (fast){
        k_mlp_mfma<<<NE/64, 256, 0, stream>>>(fw+W_BES, fw+W_WGT+OW_R10, fw+W_WGT+OW_R20,
                                              fw+W_WGT+OW_R30, (u16*)(fw + W_R));
        k_gather<<<NN/4, 256, 0, stream>>>(iw+W_OFFS, iw+W_SSND, fw+W_H,
                                           (const u16*)(fw + W_R), fw + W_A);
    } else {
        k_msg_fused<<<NN/4, 256, 0, stream>>>(iw+W_OFFS, iw+W_SSND, fw+W_H, fw+W_BES,
                                              fw+W_WGT+OW_R10, fw+W_WGT+OW_R20,
                                              fw+W_WGT+OW_R30, fw + W_A);
    }
    k_node<0><<<NN/4, 256, 0, stream>>>(fw + W_A, fw + W_NF0, fw + W_ATT,
                                        fw + W_WGT + OW_MIX0, fw + W_WGT + OW_SC0,
                                        fw + W_WGT + OW_PR0, fw + W_WGT + OW_RD0, nullptr,
                                        fw + W_NF1, d_out, iw + W_FLAG);

    // ---- interaction 1 ----
    k_h<<<NN/4, 256, 0, stream>>>(fw + W_NF1, fw + W_WGT + OW_UP1, fw + W_H);
    if (fast){
        k_mlp_mfma<<<NE/64, 256, 0, stream>>>(fw+W_BES, fw+W_WGT+OW_R11, fw+W_WGT+OW_R21,
                                              fw+W_WGT+OW_R31, (u16*)(fw + W_R));
        k_gather<<<NN/4, 256, 0, stream>>>(iw+W_OFFS, iw+W_SSND, fw+W_H,
                                           (const u16*)(fw + W_R), fw + W_A);
    } else {
        k_msg_fused<<<NN/4, 256, 0, stream>>>(iw+W_OFFS, iw+W_SSND, fw+W_H, fw+W_BES,
                                              fw+W_WGT+OW_R11, fw+W_WGT+OW_R21,
                                              fw+W_WGT+OW_R31, fw + W_A);
    }
    k_node<1><<<NN/4, 256, 0, stream>>>(fw + W_A, fw + W_NF1, fw + W_ATT,
                                        fw + W_WGT + OW_MIX1, fw + W_WGT + OW_SC1,
                                        fw + W_WGT + OW_PR1, fw + W_WGT + OW_ML1,
                                        fw + W_WGT + OW_ML2,
                                        nullptr, d_out, iw + W_FLAG);
}

// Round 9
// 287.508 us; speedup vs baseline: 4.2619x; 1.1638x over previous
//
#include <hip/hip_runtime.h>
#include <hip/hip_bf16.h>
#include <cstdint>
#include <cstddef>

#define NN 10000
#define NE 160000

typedef unsigned short u16;
typedef __attribute__((ext_vector_type(8))) short short8;
typedef __attribute__((ext_vector_type(4))) float f32x4;

__device__ __forceinline__ float b2f(u16 u){
    union { uint32_t i; float f; } v; v.i = ((uint32_t)u) << 16; return v.f;
}
__device__ __forceinline__ u16 f2b(float f){
    union { __hip_bfloat16 h; u16 u; } c; c.h = __float2bfloat16(f); return c.u;
}
__device__ __forceinline__ float silu_f(float x){ return x / (1.f + __expf(-x)); }

// ---------------- workspace layout (4-byte word offsets) ----------------
constexpr size_t W_FLAG = 0;                        // 16 (flag[0] = anomaly count)
constexpr size_t W_CNT  = 16;                       // 10000
constexpr size_t W_OFFS = 10016;                    // 10001
constexpr size_t W_CUR  = 20032;                    // 10000
constexpr size_t W_SSND = 30032;                    // 160000 (sender per sorted pos)
constexpr size_t W_INV  = 190032;                   // 160000 (edge -> sorted pos)
constexpr size_t W_ATT  = 350032;                   // 100000
constexpr size_t W_POS  = 450032;                   // 30000
constexpr size_t W_SHF  = 480032;                   // 480000
constexpr size_t W_WGT  = 960032;
constexpr size_t OW_EMB = 0;
constexpr size_t OW_UP0 = 640;
constexpr size_t OW_R10 = 4736;
constexpr size_t OW_R20 = 5248;
constexpr size_t OW_R30 = 9344;
constexpr size_t OW_MIX0= 25728;
constexpr size_t OW_SC0 = 42112;
constexpr size_t OW_PR0 = 83072;
constexpr size_t OW_UP1 = 83264;
constexpr size_t OW_R11 = 87360;
constexpr size_t OW_R21 = 87872;
constexpr size_t OW_R31 = 91968;
constexpr size_t OW_MIX1= 108352;
constexpr size_t OW_SC1 = 124736;
constexpr size_t OW_PR1 = 165696;
constexpr size_t OW_RD0 = 165888;
constexpr size_t OW_ML1 = 165952;
constexpr size_t OW_ML2 = 166976;
constexpr size_t OW_TEND = 167000;
constexpr size_t W_BES  = W_WGT + OW_TEND;          // [E][8] f32, RECEIVER-SORTED
constexpr size_t W_NF0  = W_BES + (size_t)NE*8;     // [N,64]
constexpr size_t W_H    = W_NF0 + (size_t)NN*64;
constexpr size_t W_A    = W_H   + (size_t)NN*64;
constexpr size_t W_NF1  = W_A   + (size_t)NN*64;
constexpr size_t W_R0   = W_NF1 + (size_t)NN*64;    // [E][64] bf16, RECEIVER-SORTED
constexpr size_t W_R1   = W_R0  + (size_t)NE*32;

constexpr size_t NEED_DUAL   = (W_R1 + (size_t)NE*32) * 4;  // ~60.8 MB (round-5 evidence: satisfied)
constexpr size_t NEED_SINGLE = (W_R0 + (size_t)NE*32) * 4;  // ~40.4 MB

// ---------------- dtype detection: grid-parallel anomaly count ----------------
__global__ void k_detect(const uint32_t* __restrict__ attrs, int* __restrict__ flag){
    int i = blockIdx.x * 256 + threadIdx.x;      // 196*256 = 50176 >= 50000
    int c = 0;
    if (i < 50000){
        uint32_t v = attrs[i];
        c = (v != 0u && v != 0x3F800000u) ? 1 : 0;
    }
    unsigned long long m = __ballot(c);
    if ((threadIdx.x & 63) == 0 && m)
        atomicAdd(flag, (int)__popcll(m));
}

// ---------------- convert all float inputs -> fp32 workspace ----------------
struct PrepArgs { const void* s[21]; float* d[21]; int n[21]; };
__global__ void k_prep(PrepArgs a, const int* __restrict__ flag){
    int bf = flag[0] > 100;
    int stride = gridDim.x * blockDim.x;
    int t0 = blockIdx.x * blockDim.x + threadIdx.x;
    for (int k = 0; k < 21; k++){
        float* d = a.d[k]; int n = a.n[k];
        if (bf){
            const u16* s = (const u16*)a.s[k];
            for (int i = t0; i < n; i += stride) d[i] = b2f(s[i]);
        } else {
            const float* s = (const float*)a.s[k];
            for (int i = t0; i < n; i += stride) d[i] = s[i];
        }
    }
}

// ---------------- CSR build ----------------
__global__ void k_hist(const int* __restrict__ rcv, int* __restrict__ cnt){
    int e = blockIdx.x * 256 + threadIdx.x;
    if (e < NE) atomicAdd(&cnt[rcv[e]], 1);
}
__global__ void k_scan(const int* __restrict__ cnt, int* __restrict__ offs, int* __restrict__ cur){
    __shared__ int cl[10000];
    __shared__ int part[1024];
    int t = threadIdx.x;
    for (int i = t; i < 10000; i += 1024) cl[i] = cnt[i];
    __syncthreads();
    int base = t * 10;
    int s = 0;
    #pragma unroll
    for (int i = 0; i < 10; i++) if (base + i < NN) s += cl[base + i];
    part[t] = s; __syncthreads();
    for (int d = 1; d < 1024; d <<= 1){
        int v = part[t];
        if (t >= d) v += part[t - d];
        __syncthreads();
        part[t] = v;
        __syncthreads();
    }
    int run = part[t] - s;
    #pragma unroll
    for (int i = 0; i < 10; i++){
        int idx = base + i;
        if (idx < NN){ offs[idx] = run; cur[idx] = run; run += cl[idx]; }
    }
    if (t == 1023) offs[NN] = part[1023];
}
__global__ void k_scatter(const int* __restrict__ rcv, const int* __restrict__ snd,
                          int* __restrict__ cur, int* __restrict__ ssnd, int* __restrict__ inv){
    int e = blockIdx.x * 256 + threadIdx.x;
    if (e < NE){
        int p = atomicAdd(&cur[rcv[e]], 1);
        ssnd[p] = snd[e];
        inv[e]  = p;
    }
}

// ---------------- edge bessel features, written RECEIVER-SORTED ----------------
__global__ void k_geom(const float* __restrict__ pos, const float* __restrict__ shf,
                       const int* __restrict__ snd, const int* __restrict__ rcv,
                       const int* __restrict__ inv, float* __restrict__ bessp){
    int e = blockIdx.x * 256 + threadIdx.x;
    if (e >= NE) return;
    int s = snd[e], r = rcv[e];
    float vx = pos[r*3+0] - pos[s*3+0] + shf[e*3+0];
    float vy = pos[r*3+1] - pos[s*3+1] + shf[e*3+1];
    float vz = pos[r*3+2] - pos[s*3+2] + shf[e*3+2];
    float rr = sqrtf(vx*vx + vy*vy + vz*vz);
    float xr = rr * 0.1f;
    float x2 = xr*xr; float x5 = x2*x2*xr;
    float env = 1.f - 21.f*x5 + 35.f*x5*xr - 15.f*x5*x2;
    if (xr >= 1.f) env = 0.f;
    float scl = 0.4472135954999579f * env / (rr + 1e-9f);
    float* be = bessp + (size_t)inv[e]*8;
    #pragma unroll
    for (int n = 1; n <= 8; n++)
        be[n-1] = scl * sinf((float)n * 3.14159265358979323846f * rr * 0.1f);
}

// ---------------- fused: nf0 = attrs @ w_embed, h0 = nf0 @ W_up0 ----------------
__global__ __launch_bounds__(256) void k_embed_h(const float* __restrict__ attrs,
        const float* __restrict__ Wemb, const float* __restrict__ Wup,
        float* __restrict__ nf0, float* __restrict__ h){
    int t = blockIdx.x * 256 + threadIdx.x;
    int n = t >> 6;
    int l = t & 63;
    float acc = 0.f;
    #pragma unroll
    for (int s = 0; s < 10; s++) acc += attrs[n*10 + s] * Wemb[s*64 + l];
    nf0[n*64 + l] = acc;
    float hv = 0.f;
    #pragma unroll 16
    for (int g = 0; g < 64; g++) hv += __shfl(acc, g) * Wup[g*64 + l];
    h[n*64 + l] = hv;
}

// ---------------- MFMA radial MLP (both interactions in one grid) ----------------
constexpr int OCT = 520;   // u16 per octet block (512 + 8 pad, 16B-aligned stride)

__global__ __launch_bounds__(256) void k_mlp_mfma(const float* __restrict__ bessp,
        const float* __restrict__ W1a, const float* __restrict__ W2a, const float* __restrict__ W3a,
        const float* __restrict__ W1b, const float* __restrict__ W2b, const float* __restrict__ W3b,
        u16* __restrict__ R0, u16* __restrict__ R1){
    __shared__ u16 Xa[8*OCT];   // h1 tile
    __shared__ u16 Xb[8*OCT];   // h2 tile
    __shared__ u16 Wa[8*OCT];   // W2 B-frags
    __shared__ u16 Wb[8*OCT];   // W3 (l'=0 slice) B-frags
    __shared__ u16 Xc[4*OCT];   // bess A-frags (K=32, octs 1-3 zero)
    __shared__ u16 Wc[4*OCT];   // W1 B-frags (K=32, octs 1-3 zero)
    int half = blockIdx.x >= 2500;
    int blk  = half ? blockIdx.x - 2500 : blockIdx.x;
    const float* W1 = half ? W1b : W1a;
    const float* W2 = half ? W2b : W2a;
    const float* W3 = half ? W3b : W3a;
    u16* R = half ? R1 : R0;
    int t = threadIdx.x;
    int w = t >> 6, lane = t & 63;
    int q = lane >> 4, r = lane & 15;
    int pbase = blk * 64;                        // 2500 * 64 == NE

    for (int i = t; i < 4*OCT/8; i += 256){
        ((short8*)Xc)[i] = (short8)0;
        ((short8*)Wc)[i] = (short8)0;
    }
    for (int i = t; i < 2048; i += 256){
        int k = (i >> 6) * 2, n = i & 63;
        uint32_t w2p = ((uint32_t)f2b(W2[(k+1)*64 + n]) << 16) | f2b(W2[k*64 + n]);
        uint32_t w3p = ((uint32_t)f2b(W3[(k+1)*256 + 4*n]) << 16) | f2b(W3[k*256 + 4*n]);
        *(uint32_t*)&Wa[(k>>3)*OCT + n*8 + (k&7)] = w2p;
        *(uint32_t*)&Wb[(k>>3)*OCT + n*8 + (k&7)] = w3p;
    }
    __syncthreads();   // zeros visible before oct0 fill
    for (int i = t; i < 512; i += 256){
        int k = i >> 6, n = i & 63;
        Wc[n*8 + k] = f2b(W1[i]);
    }
    for (int i = t; i < 512; i += 256){
        Xc[i] = f2b(bessp[(size_t)pbase*8 + i]);
    }
    __syncthreads();

    int et = w;
    int erow = et*16 + r;
    // ---- layer 1: K=8 (padded to 32) ----
    {
        short8 a = *(const short8*)&Xc[q*OCT + erow*8];
        #pragma unroll
        for (int nt = 0; nt < 4; nt++){
            short8 b = *(const short8*)&Wc[q*OCT + (nt*16 + r)*8];
            f32x4 c = {0.f, 0.f, 0.f, 0.f};
            c = __builtin_amdgcn_mfma_f32_16x16x32_bf16(a, b, c, 0, 0, 0);
            #pragma unroll
            for (int g = 0; g < 4; g++){
                int e = et*16 + q*4 + g;
                int n = nt*16 + r;
                Xa[(n>>3)*OCT + e*8 + (n&7)] = f2b(silu_f(c[g]));
            }
        }
    }
    __syncthreads();
    // ---- layer 2: K=64 ----
    {
        short8 a0 = *(const short8*)&Xa[q*OCT + erow*8];
        short8 a1 = *(const short8*)&Xa[(4+q)*OCT + erow*8];
        #pragma unroll
        for (int nt = 0; nt < 4; nt++){
            short8 b0 = *(const short8*)&Wa[q*OCT + (nt*16 + r)*8];
            short8 b1 = *(const short8*)&Wa[(4+q)*OCT + (nt*16 + r)*8];
            f32x4 c = {0.f, 0.f, 0.f, 0.f};
            c = __builtin_amdgcn_mfma_f32_16x16x32_bf16(a0, b0, c, 0, 0, 0);
            c = __builtin_amdgcn_mfma_f32_16x16x32_bf16(a1, b1, c, 0, 0, 0);
            #pragma unroll
            for (int g = 0; g < 4; g++){
                int e = et*16 + q*4 + g;
                int n = nt*16 + r;
                Xb[(n>>3)*OCT + e*8 + (n&7)] = f2b(silu_f(c[g]));
            }
        }
    }
    __syncthreads();
    // ---- layer 3: K=64, store R (bf16, receiver-sorted) ----
    {
        short8 a0 = *(const short8*)&Xb[q*OCT + erow*8];
        short8 a1 = *(const short8*)&Xb[(4+q)*OCT + erow*8];
        #pragma unroll
        for (int nt = 0; nt < 4; nt++){
            short8 b0 = *(const short8*)&Wb[q*OCT + (nt*16 + r)*8];
            short8 b1 = *(const short8*)&Wb[(4+q)*OCT + (nt*16 + r)*8];
            f32x4 c = {0.f, 0.f, 0.f, 0.f};
            c = __builtin_amdgcn_mfma_f32_16x16x32_bf16(a0, b0, c, 0, 0, 0);
            c = __builtin_amdgcn_mfma_f32_16x16x32_bf16(a1, b1, c, 0, 0, 0);
            #pragma unroll
            for (int g = 0; g < 4; g++){
                int e = et*16 + q*4 + g;
                int n = nt*16 + r;
                R[(size_t)(pbase + e)*64 + n] = f2b(c[g]);
            }
        }
    }
}

// ---------------- CSR gather-sum: A[n,f] = (1/16) sum_p h[ssnd[p],f] * R[p,f] ----------------
__global__ __launch_bounds__(256) void k_gather(const int* __restrict__ offs,
        const int* __restrict__ ssnd, const float* __restrict__ h,
        const u16* __restrict__ R, float* __restrict__ A){
    int wv = threadIdx.x >> 6;
    int n  = blockIdx.x * 4 + wv;
    int l  = threadIdx.x & 63;
    int beg = __builtin_amdgcn_readfirstlane(offs[n]);
    int end = __builtin_amdgcn_readfirstlane(offs[n+1]);
    float acc = 0.f;
    int p = beg;
    for (; p + 4 <= end; p += 4){
        int s0 = __builtin_amdgcn_readfirstlane(ssnd[p+0]);
        int s1 = __builtin_amdgcn_readfirstlane(ssnd[p+1]);
        int s2 = __builtin_amdgcn_readfirstlane(ssnd[p+2]);
        int s3 = __builtin_amdgcn_readfirstlane(ssnd[p+3]);
        float r0 = b2f(R[(size_t)(p+0)*64 + l]);
        float r1 = b2f(R[(size_t)(p+1)*64 + l]);
        float r2 = b2f(R[(size_t)(p+2)*64 + l]);
        float r3 = b2f(R[(size_t)(p+3)*64 + l]);
        float h0v = h[s0*64 + l];
        float h1v = h[s1*64 + l];
        float h2v = h[s2*64 + l];
        float h3v = h[s3*64 + l];
        acc += h0v*r0 + h1v*r1 + h2v*r2 + h3v*r3;
    }
    for (; p < end; p++){
        int s = __builtin_amdgcn_readfirstlane(ssnd[p]);
        acc += h[s*64 + l] * b2f(R[(size_t)p*64 + l]);
    }
    A[n*64 + l] = acc * 0.0625f;
}

// ---------------- legacy fused msg (fallback when ws too small) ----------------
__global__ __launch_bounds__(256) void k_msg_fused(const int* __restrict__ offs,
        const int* __restrict__ ssnd, const float* __restrict__ h, const float* __restrict__ bessp,
        const float* __restrict__ W1, const float* __restrict__ W2, const float* __restrict__ W3,
        float* __restrict__ A){
    int wv = threadIdx.x >> 6;
    int n  = blockIdx.x * 4 + wv;
    int l  = threadIdx.x & 63;
    float w1c[8];
    #pragma unroll
    for (int i = 0; i < 8; i++) w1c[i] = W1[i*64 + l];
    float w2c[64];
    #pragma unroll
    for (int j = 0; j < 64; j++) w2c[j] = W2[j*64 + l];
    float w3c[64];
    #pragma unroll
    for (int j = 0; j < 64; j++) w3c[j] = W3[j*256 + 4*l];
    float acc = 0.f;
    int beg = __builtin_amdgcn_readfirstlane(offs[n]);
    int end = __builtin_amdgcn_readfirstlane(offs[n+1]);
    for (int p = beg; p < end; p++){
        int s = __builtin_amdgcn_readfirstlane(ssnd[p]);
        const float* be = bessp + (size_t)p*8;
        float h1 = 0.f;
        #pragma unroll
        for (int i = 0; i < 8; i++) h1 += be[i] * w1c[i];
        h1 = silu_f(h1);
        float h2 = 0.f;
        #pragma unroll
        for (int j = 0; j < 64; j++) h2 += __shfl(h1, j) * w2c[j];
        h2 = silu_f(h2);
        float rr = 0.f;
        #pragma unroll
        for (int j = 0; j < 64; j++) rr += __shfl(h2, j) * w3c[j];
        acc += h[s*64 + l] * rr;
    }
    A[n*64 + l] = acc * 0.0625f;
}

// ---------------- node update (mix k=0 + sc + poly) + readout (+h for next layer) ----------------
template<int LAST>
__global__ __launch_bounds__(256) void k_node(const float* __restrict__ A, const float* __restrict__ nf,
        const float* __restrict__ attrs, const float* __restrict__ Wmix0, const float* __restrict__ Wsc,
        const float* __restrict__ Wprod, const float* __restrict__ Wtail, const float* __restrict__ Wml2,
        const float* __restrict__ Wup1, float* __restrict__ nf1out, float* __restrict__ hout,
        void* __restrict__ out, const int* __restrict__ flag){
    int wv = threadIdx.x >> 6;
    int n  = blockIdx.x * 4 + wv;
    int l  = threadIdx.x & 63;
    float Af  = A[n*64 + l];
    float nff = nf[n*64 + l];
    float am = 0.f;
    #pragma unroll 16
    for (int f = 0; f < 64; f++) am += __shfl(Af, f) * Wmix0[f*64 + l];
    float sc = 0.f;
    for (int s = 0; s < 10; s++){
        float av = attrs[n*10 + s];       // wave-uniform
        if (av != 0.f){
            const float* Ws = Wsc + s*4096;
            float t = 0.f;
            #pragma unroll 16
            for (int f = 0; f < 64; f++) t += __shfl(nff, f) * Ws[f*64 + l];
            sc += av * t;
        }
    }
    float poly = Wprod[l] + Wprod[64 + l]*am + Wprod[128 + l]*am*am;
    float val = am*poly + sc;
    float rv;
    if (LAST == 0){
        nf1out[n*64 + l] = val;
        float hv = 0.f;
        #pragma unroll 16
        for (int g = 0; g < 64; g++) hv += __shfl(val, g) * Wup1[g*64 + l];
        hout[n*64 + l] = hv;
        rv = val * Wtail[l];
    } else {
        int lj = l & 15;           // all 64 lanes run the shfl loop (divergent shfl is UB)
        float t = 0.f;
        #pragma unroll 16
        for (int g = 0; g < 64; g++){
            float vg = __shfl(val, g);
            t += vg * Wtail[g*16 + lj];
        }
        rv = (l < 16) ? (silu_f(t) * Wml2[lj]) : 0.f;
    }
    #pragma unroll
    for (int o2 = 32; o2; o2 >>= 1) rv += __shfl_down(rv, o2);
    if (l == 0){
        int idx = 2*n + LAST;
        if (flag[0] > 100) ((__hip_bfloat16*)out)[idx] = __float2bfloat16(rv);
        else               ((float*)out)[idx] = rv;
    }
}

// ---------------- launch ----------------
extern "C" void kernel_launch(void* const* d_in, const int* in_sizes, int n_in,
                              void* d_out, int out_size, void* d_ws, size_t ws_size,
                              hipStream_t stream) {
    int*   iw = (int*)d_ws;
    float* fw = (float*)d_ws;
    const int* snd = (const int*)d_in[3];
    const int* rcv = (const int*)d_in[4];

    PrepArgs pa;
    const int    pidx[21] = {0,1,2, 5,6,7,8,9,10,11,12,13,14,15,16,17,18,19,20,21,22};
    const size_t pdst[21] = {W_POS, W_ATT, W_SHF,
        W_WGT+OW_EMB, W_WGT+OW_UP0, W_WGT+OW_R10, W_WGT+OW_R20, W_WGT+OW_R30,
        W_WGT+OW_MIX0, W_WGT+OW_SC0, W_WGT+OW_PR0,
        W_WGT+OW_UP1, W_WGT+OW_R11, W_WGT+OW_R21, W_WGT+OW_R31,
        W_WGT+OW_MIX1, W_WGT+OW_SC1, W_WGT+OW_PR1,
        W_WGT+OW_RD0, W_WGT+OW_ML1, W_WGT+OW_ML2};
    const int    pn[21]   = {30000, 100000, 480000,
        640, 4096, 512, 4096, 16384, 16384, 40960, 192,
        4096, 512, 4096, 16384, 16384, 40960, 192, 64, 1024, 16};
    for (int i = 0; i < 21; i++){
        pa.s[i] = d_in[pidx[i]];
        pa.d[i] = fw + pdst[i];
        pa.n[i] = pn[i];
    }

    const int dual   = (ws_size >= NEED_DUAL);
    const int single = (!dual && ws_size >= NEED_SINGLE);

    hipMemsetAsync(iw, 0, (W_CNT + NN) * sizeof(int), stream);   // flag + cnt
    k_detect<<<196, 256, 0, stream>>>((const uint32_t*)d_in[1], iw + W_FLAG);
    k_prep<<<120, 256, 0, stream>>>(pa, iw + W_FLAG);
    k_hist<<<NE/256, 256, 0, stream>>>(rcv, iw + W_CNT);
    k_scan<<<1, 1024, 0, stream>>>(iw + W_CNT, iw + W_OFFS, iw + W_CUR);
    k_scatter<<<NE/256, 256, 0, stream>>>(rcv, snd, iw + W_CUR, iw + W_SSND, iw + W_INV);
    k_geom<<<NE/256, 256, 0, stream>>>(fw + W_POS, fw + W_SHF, snd, rcv, iw + W_INV, fw + W_BES);
    k_embed_h<<<NN/4, 256, 0, stream>>>(fw + W_ATT, fw + W_WGT + OW_EMB, fw + W_WGT + OW_UP0,
                                        fw + W_NF0, fw + W_H);
    if (dual){
        k_mlp_mfma<<<5000, 256, 0, stream>>>(fw+W_BES,
            fw+W_WGT+OW_R10, fw+W_WGT+OW_R20, fw+W_WGT+OW_R30,
            fw+W_WGT+OW_R11, fw+W_WGT+OW_R21, fw+W_WGT+OW_R31,
            (u16*)(fw + W_R0), (u16*)(fw + W_R1));
        k_gather<<<NN/4, 256, 0, stream>>>(iw+W_OFFS, iw+W_SSND, fw+W_H,
                                           (const u16*)(fw + W_R0), fw + W_A);
    } else if (single){
        k_mlp_mfma<<<2500, 256, 0, stream>>>(fw+W_BES,
            fw+W_WGT+OW_R10, fw+W_WGT+OW_R20, fw+W_WGT+OW_R30,
            fw+W_WGT+OW_R10, fw+W_WGT+OW_R20, fw+W_WGT+OW_R30,
            (u16*)(fw + W_R0), (u16*)(fw + W_R0));
        k_gather<<<NN/4, 256, 0, stream>>>(iw+W_OFFS, iw+W_SSND, fw+W_H,
                                           (const u16*)(fw + W_R0), fw + W_A);
    } else {
        k_msg_fused<<<NN/4, 256, 0, stream>>>(iw+W_OFFS, iw+W_SSND, fw+W_H, fw+W_BES,
                                              fw+W_WGT+OW_R10, fw+W_WGT+OW_R20,
                                              fw+W_WGT+OW_R30, fw + W_A);
    }
    k_node<0><<<NN/4, 256, 0, stream>>>(fw + W_A, fw + W_NF0, fw + W_ATT,
                                        fw + W_WGT + OW_MIX0, fw + W_WGT + OW_SC0,
                                        fw + W_WGT + OW_PR0, fw + W_WGT + OW_RD0, nullptr,
                                        fw + W_WGT + OW_UP1, fw + W_NF1, fw + W_H,
                                        d_out, iw + W_FLAG);
    // ---- interaction 1 ----
    if (dual){
        k_gather<<<NN/4, 256, 0, stream>>>(iw+W_OFFS, iw+W_SSND, fw+W_H,
                                           (const u16*)(fw + W_R1), fw + W_A);
    } else if (single){
        k_mlp_mfma<<<2500, 256, 0, stream>>>(fw+W_BES,
            fw+W_WGT+OW_R11, fw+W_WGT+OW_R21, fw+W_WGT+OW_R31,
            fw+W_WGT+OW_R11, fw+W_WGT+OW_R21, fw+W_WGT+OW_R31,
            (u16*)(fw + W_R0), (u16*)(fw + W_R0));
        k_gather<<<NN/4, 256, 0, stream>>>(iw+W_OFFS, iw+W_SSND, fw+W_H,
                                           (const u16*)(fw + W_R0), fw + W_A);
    } else {
        k_msg_fused<<<NN/4, 256, 0, stream>>>(iw+W_OFFS, iw+W_SSND, fw+W_H, fw+W_BES,
                                              fw+W_WGT+OW_R11, fw+W_WGT+OW_R21,
                                              fw+W_WGT+OW_R31, fw + W_A);
    }
    k_node<1><<<NN/4, 256, 0, stream>>>(fw + W_A, fw + W_NF1, fw + W_ATT,
                                        fw + W_WGT + OW_MIX1, fw + W_WGT + OW_SC1,
                                        fw + W_WGT + OW_PR1, fw + W_WGT + OW_ML1,
                                        fw + W_WGT + OW_ML2, nullptr, nullptr, nullptr,
                                        d_out, iw + W_FLAG);
}

// Round 11
// 276.557 us; speedup vs baseline: 4.4307x; 1.0396x over previous
//
#include <hip/hip_runtime.h>
#include <hip/hip_bf16.h>
#include <cstdint>
#include <cstddef>

#define NN 10000
#define NE 160000

typedef unsigned short u16;
typedef __attribute__((ext_vector_type(8))) short short8;
typedef __attribute__((ext_vector_type(4))) float f32x4;

__device__ __forceinline__ float b2f(u16 u){
    union { uint32_t i; float f; } v; v.i = ((uint32_t)u) << 16; return v.f;
}
__device__ __forceinline__ u16 f2b(float f){
    union { __hip_bfloat16 h; u16 u; } c; c.h = __float2bfloat16(f); return c.u;
}
__device__ __forceinline__ float silu_f(float x){ return x / (1.f + __expf(-x)); }

// ---------------- workspace layout (4-byte word offsets) ----------------
constexpr size_t W_FLAG = 0;                        // 16 (flag[0] = anomaly count)
constexpr size_t W_CNT  = 16;                       // 10000
constexpr size_t W_OFFS = 10016;                    // 10001
constexpr size_t W_CUR  = 20032;                    // 10000
constexpr size_t W_SSND = 30032;                    // 160000 (sender per sorted pos)
constexpr size_t W_INV  = 190032;                   // 160000 (edge -> sorted pos)
constexpr size_t W_ATT  = 350032;                   // 100000
constexpr size_t W_POS  = 450032;                   // 30000
constexpr size_t W_SHF  = 480032;                   // 480000
constexpr size_t W_WGT  = 960032;
constexpr size_t OW_EMB = 0;
constexpr size_t OW_UP0 = 640;
constexpr size_t OW_R10 = 4736;
constexpr size_t OW_R20 = 5248;
constexpr size_t OW_R30 = 9344;
constexpr size_t OW_MIX0= 25728;
constexpr size_t OW_SC0 = 42112;
constexpr size_t OW_PR0 = 83072;
constexpr size_t OW_UP1 = 83264;
constexpr size_t OW_R11 = 87360;
constexpr size_t OW_R21 = 87872;
constexpr size_t OW_R31 = 91968;
constexpr size_t OW_MIX1= 108352;
constexpr size_t OW_SC1 = 124736;
constexpr size_t OW_PR1 = 165696;
constexpr size_t OW_RD0 = 165888;
constexpr size_t OW_ML1 = 165952;
constexpr size_t OW_ML2 = 166976;
constexpr size_t OW_TEND = 167000;
constexpr size_t W_BES  = W_WGT + OW_TEND;          // [E][8] f32, RECEIVER-SORTED
constexpr size_t W_NF0  = W_BES + (size_t)NE*8;     // [N,64]
constexpr size_t W_H    = W_NF0 + (size_t)NN*64;
constexpr size_t W_A    = W_H   + (size_t)NN*64;
constexpr size_t W_NF1  = W_A   + (size_t)NN*64;
constexpr size_t W_R0   = W_NF1 + (size_t)NN*64;    // [E][64] bf16, RECEIVER-SORTED
constexpr size_t W_R1   = W_R0  + (size_t)NE*32;
// rs (sorted edge distances) overlays the head of R0: consumed by k_bess BEFORE k_mlp writes R0.
// packed weights: 2 interactions x 10400 u16 = 2 x 5200 words
constexpr size_t WP_DUAL   = W_R1 + (size_t)NE*32;
constexpr size_t WP_SINGLE = W_R0 + (size_t)NE*32;

constexpr size_t NEED_DUAL   = (WP_DUAL   + 10400) * 4;  // ~60.87 MB (round-5 evidence: ws >= 60.90 MB)
constexpr size_t NEED_SINGLE = (WP_SINGLE + 10400) * 4;  // ~40.5 MB

constexpr int OCT  = 520;   // weight per-oct stride (u16)
constexpr int OCTS = 136;   // activation per-oct stride (u16), 16 rows

// ---------------- dtype detection: grid-parallel anomaly count ----------------
__global__ void k_detect(const uint32_t* __restrict__ attrs, int* __restrict__ flag){
    int i = blockIdx.x * 256 + threadIdx.x;
    int c = 0;
    if (i < 50000){
        uint32_t v = attrs[i];
        c = (v != 0u && v != 0x3F800000u) ? 1 : 0;
    }
    unsigned long long m = __ballot(c);
    if ((threadIdx.x & 63) == 0 && m)
        atomicAdd(flag, (int)__popcll(m));
}

// ---------------- convert all float inputs -> fp32 workspace ----------------
struct PrepArgs { const void* s[21]; float* d[21]; int n[21]; };
__global__ void k_prep(PrepArgs a, const int* __restrict__ flag){
    int bf = flag[0] > 100;
    int stride = gridDim.x * blockDim.x;
    int t0 = blockIdx.x * blockDim.x + threadIdx.x;
    for (int k = 0; k < 21; k++){
        float* d = a.d[k]; int n = a.n[k];
        if (bf){
            const u16* s = (const u16*)a.s[k];
            for (int i = t0; i < n; i += stride) d[i] = b2f(s[i]);
        } else {
            const float* s = (const float*)a.s[k];
            for (int i = t0; i < n; i += stride) d[i] = s[i];
        }
    }
}

// ---------------- pre-pack radial weights into B-fragment bf16 layout ----------------
// Per interaction (block b): dst = WP + b*10400 u16.
//  [0,2080)  : W1 frags, oct stride OCT, oct0 = [n][k], octs1-3 zero
//  [2080,6240): W2 frags [oct][n*8 + k&7]
//  [6240,10400): W3 (l'=0 slice) frags
__global__ void k_wpack(const float* __restrict__ Wg, u16* __restrict__ WP){
    int b = blockIdx.x;
    const float* W1 = Wg + (b ? OW_R11 : OW_R10);
    const float* W2 = Wg + (b ? OW_R21 : OW_R20);
    const float* W3 = Wg + (b ? OW_R31 : OW_R30);
    u16* dst = WP + b * 10400;
    int t = threadIdx.x;
    for (int i = t; i < 5200; i += 256) ((uint32_t*)dst)[i] = 0;   // zero ALL 10400 u16
    __syncthreads();
    for (int i = t; i < 512; i += 256){
        int n = i >> 3, k = i & 7;
        dst[n*8 + k] = f2b(W1[k*64 + n]);
    }
    for (int i = t; i < 2048; i += 256){
        int k = (i >> 6) * 2, n = i & 63;
        uint32_t p2 = ((uint32_t)f2b(W2[(k+1)*64 + n]) << 16) | f2b(W2[k*64 + n]);
        uint32_t p3 = ((uint32_t)f2b(W3[(k+1)*256 + 4*n]) << 16) | f2b(W3[k*256 + 4*n]);
        *(uint32_t*)&dst[2080 + (k>>3)*OCT + n*8 + (k&7)] = p2;
        *(uint32_t*)&dst[6240 + (k>>3)*OCT + n*8 + (k&7)] = p3;
    }
}

// ---------------- CSR build ----------------
__global__ void k_hist(const int* __restrict__ rcv, int* __restrict__ cnt){
    int e = blockIdx.x * 256 + threadIdx.x;
    if (e < NE) atomicAdd(&cnt[rcv[e]], 1);
}
__global__ void k_scan(const int* __restrict__ cnt, int* __restrict__ offs, int* __restrict__ cur){
    __shared__ int cl[10000];
    __shared__ int part[1024];
    int t = threadIdx.x;
    for (int i = t; i < 10000; i += 1024) cl[i] = cnt[i];
    __syncthreads();
    int base = t * 10;
    int s = 0;
    #pragma unroll
    for (int i = 0; i < 10; i++) if (base + i < NN) s += cl[base + i];
    part[t] = s; __syncthreads();
    for (int d = 1; d < 1024; d <<= 1){
        int v = part[t];
        if (t >= d) v += part[t - d];
        __syncthreads();
        part[t] = v;
        __syncthreads();
    }
    int run = part[t] - s;
    #pragma unroll
    for (int i = 0; i < 10; i++){
        int idx = base + i;
        if (idx < NN){ offs[idx] = run; cur[idx] = run; run += cl[idx]; }
    }
    if (t == 1023) offs[NN] = part[1023];
}
__global__ void k_scatter(const int* __restrict__ rcv, const int* __restrict__ snd,
                          int* __restrict__ cur, int* __restrict__ ssnd, int* __restrict__ inv){
    int e = blockIdx.x * 256 + threadIdx.x;
    if (e < NE){
        int p = atomicAdd(&cur[rcv[e]], 1);
        ssnd[p] = snd[e];
        inv[e]  = p;
    }
}

// ---------------- edge distance -> sorted slot (4 B scatter) ----------------
__global__ void k_geom_r(const float* __restrict__ pos, const float* __restrict__ shf,
                         const int* __restrict__ snd, const int* __restrict__ rcv,
                         const int* __restrict__ inv, float* __restrict__ rs){
    int e = blockIdx.x * 256 + threadIdx.x;
    if (e >= NE) return;
    int s = snd[e], r = rcv[e];
    float vx = pos[r*3+0] - pos[s*3+0] + shf[e*3+0];
    float vy = pos[r*3+1] - pos[s*3+1] + shf[e*3+1];
    float vz = pos[r*3+2] - pos[s*3+2] + shf[e*3+2];
    rs[inv[e]] = sqrtf(vx*vx + vy*vy + vz*vz);
}
// ---------------- bessel from sorted distances (fully coalesced) ----------------
__global__ void k_bess(const float* __restrict__ rs, float* __restrict__ bessp){
    int p = blockIdx.x * 256 + threadIdx.x;
    if (p >= NE) return;
    float rr = rs[p];
    float xr = rr * 0.1f;
    float x2 = xr*xr; float x5 = x2*x2*xr;
    float env = 1.f - 21.f*x5 + 35.f*x5*xr - 15.f*x5*x2;
    if (xr >= 1.f) env = 0.f;
    float scl = 0.4472135954999579f * env / (rr + 1e-9f);
    float b[8];
    #pragma unroll
    for (int n = 1; n <= 8; n++)
        b[n-1] = scl * sinf((float)n * 3.14159265358979323846f * rr * 0.1f);
    float4* be = (float4*)(bessp + (size_t)p*8);
    be[0] = make_float4(b[0], b[1], b[2], b[3]);
    be[1] = make_float4(b[4], b[5], b[6], b[7]);
}
// ---------------- legacy full geom (fallback tier only) ----------------
__global__ void k_geom_full(const float* __restrict__ pos, const float* __restrict__ shf,
                            const int* __restrict__ snd, const int* __restrict__ rcv,
                            const int* __restrict__ inv, float* __restrict__ bessp){
    int e = blockIdx.x * 256 + threadIdx.x;
    if (e >= NE) return;
    int s = snd[e], r = rcv[e];
    float vx = pos[r*3+0] - pos[s*3+0] + shf[e*3+0];
    float vy = pos[r*3+1] - pos[s*3+1] + shf[e*3+1];
    float vz = pos[r*3+2] - pos[s*3+2] + shf[e*3+2];
    float rr = sqrtf(vx*vx + vy*vy + vz*vz);
    float xr = rr * 0.1f;
    float x2 = xr*xr; float x5 = x2*x2*xr;
    float env = 1.f - 21.f*x5 + 35.f*x5*xr - 15.f*x5*x2;
    if (xr >= 1.f) env = 0.f;
    float scl = 0.4472135954999579f * env / (rr + 1e-9f);
    float* be = bessp + (size_t)inv[e]*8;
    #pragma unroll
    for (int n = 1; n <= 8; n++)
        be[n-1] = scl * sinf((float)n * 3.14159265358979323846f * rr * 0.1f);
}

// ---------------- fused: nf0 = attrs @ w_embed, h0 = nf0 @ W_up0 ----------------
__global__ __launch_bounds__(256) void k_embed_h(const float* __restrict__ attrs,
        const float* __restrict__ Wemb, const float* __restrict__ Wup,
        float* __restrict__ nf0, float* __restrict__ h){
    int t = blockIdx.x * 256 + threadIdx.x;
    int n = t >> 6;
    int l = t & 63;
    float acc = 0.f;
    #pragma unroll
    for (int s = 0; s < 10; s++) acc += attrs[n*10 + s] * Wemb[s*64 + l];
    nf0[n*64 + l] = acc;
    float hv = 0.f;
    #pragma unroll 16
    for (int g = 0; g < 64; g++) hv += __shfl(acc, g) * Wup[g*64 + l];
    h[n*64 + l] = hv;
}

// ---------------- MFMA radial MLP: block = 256 edges, pre-packed weights ----------------
// Wave owns 64 edges (4 subtiles of 16); per-wave private LDS activation regions ->
// no block barriers in the subtile loop. X[w]: octs [0..3]=Xc(bess), [4..11]=Xa, [12..19]=Xb.
__global__ __launch_bounds__(256) void k_mlp_mfma(const float* __restrict__ bessp,
        const u16* __restrict__ WPa, const u16* __restrict__ WPb,
        u16* __restrict__ R0, u16* __restrict__ R1){
    __shared__ __align__(16) u16 W[10400];
    __shared__ __align__(16) u16 X[4][20*OCTS];
    int half = blockIdx.x >= 625;
    int blk  = half ? blockIdx.x - 625 : blockIdx.x;
    const u16* WP = half ? WPb : WPa;
    u16* R = half ? R1 : R0;
    int t = threadIdx.x;
    int w = t >> 6, lane = t & 63;
    int q = lane >> 4, r = lane & 15;
    u16* Xw = &X[w][0];
    // stage pre-packed weights: pure vector copy.
    // 10400 u16 = 20800 B = 1300 uint4   (round-10 bug: copied only 650 -> half of W was garbage)
    for (int i = t; i < 1300; i += 256) ((uint4*)W)[i] = ((const uint4*)WP)[i];
    // zero Xc octs 1..3 (K-padding), per-wave region
    {
        uint32_t* xz = (uint32_t*)(Xw + OCTS);
        for (int i = lane; i < 204; i += 64) xz[i] = 0;
    }
    __syncthreads();
    int pbase = blk * 256 + w * 64;
    #pragma unroll 1
    for (int st = 0; st < 4; st++){
        int pb = pbase + st * 16;
        // stage bess subtile -> Xc oct0 [e][k] (one packed dword per lane)
        {
            float2 bv = *(const float2*)(bessp + (size_t)pb*8 + 2*lane);
            ((uint32_t*)Xw)[lane] = ((uint32_t)f2b(bv.y) << 16) | f2b(bv.x);
        }
        // ---- layer 1: K=8 (padded to 32) ----
        {
            short8 a = *(const short8*)&Xw[q*OCTS + r*8];
            #pragma unroll
            for (int nt = 0; nt < 4; nt++){
                short8 b = *(const short8*)&W[q*OCT + (nt*16 + r)*8];
                f32x4 c = {0.f, 0.f, 0.f, 0.f};
                c = __builtin_amdgcn_mfma_f32_16x16x32_bf16(a, b, c, 0, 0, 0);
                #pragma unroll
                for (int g = 0; g < 4; g++){
                    int e = q*4 + g;
                    int n = nt*16 + r;
                    Xw[(4 + (n>>3))*OCTS + e*8 + (n&7)] = f2b(silu_f(c[g]));
                }
            }
        }
        // ---- layer 2: K=64 ----
        {
            short8 a0 = *(const short8*)&Xw[(4+q)*OCTS + r*8];
            short8 a1 = *(const short8*)&Xw[(8+q)*OCTS + r*8];
            #pragma unroll
            for (int nt = 0; nt < 4; nt++){
                short8 b0 = *(const short8*)&W[2080 + q*OCT + (nt*16 + r)*8];
                short8 b1 = *(const short8*)&W[2080 + (4+q)*OCT + (nt*16 + r)*8];
                f32x4 c = {0.f, 0.f, 0.f, 0.f};
                c = __builtin_amdgcn_mfma_f32_16x16x32_bf16(a0, b0, c, 0, 0, 0);
                c = __builtin_amdgcn_mfma_f32_16x16x32_bf16(a1, b1, c, 0, 0, 0);
                #pragma unroll
                for (int g = 0; g < 4; g++){
                    int e = q*4 + g;
                    int n = nt*16 + r;
                    Xw[(12 + (n>>3))*OCTS + e*8 + (n&7)] = f2b(silu_f(c[g]));
                }
            }
        }
        // ---- layer 3: K=64, store R (bf16, receiver-sorted) ----
        {
            short8 a0 = *(const short8*)&Xw[(12+q)*OCTS + r*8];
            short8 a1 = *(const short8*)&Xw[(16+q)*OCTS + r*8];
            #pragma unroll
            for (int nt = 0; nt < 4; nt++){
                short8 b0 = *(const short8*)&W[6240 + q*OCT + (nt*16 + r)*8];
                short8 b1 = *(const short8*)&W[6240 + (4+q)*OCT + (nt*16 + r)*8];
                f32x4 c = {0.f, 0.f, 0.f, 0.f};
                c = __builtin_amdgcn_mfma_f32_16x16x32_bf16(a0, b0, c, 0, 0, 0);
                c = __builtin_amdgcn_mfma_f32_16x16x32_bf16(a1, b1, c, 0, 0, 0);
                #pragma unroll
                for (int g = 0; g < 4; g++){
                    int e = q*4 + g;
                    int n = nt*16 + r;
                    R[(size_t)(pb + e)*64 + n] = f2b(c[g]);
                }
            }
        }
    }
}

// ---------------- CSR gather-sum: A[n,f] = (1/16) sum_p h[ssnd[p],f] * R[p,f] ----------------
__global__ __launch_bounds__(256) void k_gather(const int* __restrict__ offs,
        const int* __restrict__ ssnd, const float* __restrict__ h,
        const u16* __restrict__ R, float* __restrict__ A){
    int wv = threadIdx.x >> 6;
    int n  = blockIdx.x * 4 + wv;
    int l  = threadIdx.x & 63;
    int beg = __builtin_amdgcn_readfirstlane(offs[n]);
    int end = __builtin_amdgcn_readfirstlane(offs[n+1]);
    float acc = 0.f;
    int p = beg;
    for (; p + 4 <= end; p += 4){
        int s0 = __builtin_amdgcn_readfirstlane(ssnd[p+0]);
        int s1 = __builtin_amdgcn_readfirstlane(ssnd[p+1]);
        int s2 = __builtin_amdgcn_readfirstlane(ssnd[p+2]);
        int s3 = __builtin_amdgcn_readfirstlane(ssnd[p+3]);
        float r0 = b2f(R[(size_t)(p+0)*64 + l]);
        float r1 = b2f(R[(size_t)(p+1)*64 + l]);
        float r2 = b2f(R[(size_t)(p+2)*64 + l]);
        float r3 = b2f(R[(size_t)(p+3)*64 + l]);
        float h0v = h[s0*64 + l];
        float h1v = h[s1*64 + l];
        float h2v = h[s2*64 + l];
        float h3v = h[s3*64 + l];
        acc += h0v*r0 + h1v*r1 + h2v*r2 + h3v*r3;
    }
    for (; p < end; p++){
        int s = __builtin_amdgcn_readfirstlane(ssnd[p]);
        acc += h[s*64 + l] * b2f(R[(size_t)p*64 + l]);
    }
    A[n*64 + l] = acc * 0.0625f;
}

// ---------------- legacy fused msg (fallback when ws too small) ----------------
__global__ __launch_bounds__(256) void k_msg_fused(const int* __restrict__ offs,
        const int* __restrict__ ssnd, const float* __restrict__ h, const float* __restrict__ bessp,
        const float* __restrict__ W1, const float* __restrict__ W2, const float* __restrict__ W3,
        float* __restrict__ A){
    int wv = threadIdx.x >> 6;
    int n  = blockIdx.x * 4 + wv;
    int l  = threadIdx.x & 63;
    float w1c[8];
    #pragma unroll
    for (int i = 0; i < 8; i++) w1c[i] = W1[i*64 + l];
    float w2c[64];
    #pragma unroll
    for (int j = 0; j < 64; j++) w2c[j] = W2[j*64 + l];
    float w3c[64];
    #pragma unroll
    for (int j = 0; j < 64; j++) w3c[j] = W3[j*256 + 4*l];
    float acc = 0.f;
    int beg = __builtin_amdgcn_readfirstlane(offs[n]);
    int end = __builtin_amdgcn_readfirstlane(offs[n+1]);
    for (int p = beg; p < end; p++){
        int s = __builtin_amdgcn_readfirstlane(ssnd[p]);
        const float* be = bessp + (size_t)p*8;
        float h1 = 0.f;
        #pragma unroll
        for (int i = 0; i < 8; i++) h1 += be[i] * w1c[i];
        h1 = silu_f(h1);
        float h2 = 0.f;
        #pragma unroll
        for (int j = 0; j < 64; j++) h2 += __shfl(h1, j) * w2c[j];
        h2 = silu_f(h2);
        float rr = 0.f;
        #pragma unroll
        for (int j = 0; j < 64; j++) rr += __shfl(h2, j) * w3c[j];
        acc += h[s*64 + l] * rr;
    }
    A[n*64 + l] = acc * 0.0625f;
}

// ---------------- node update (mix k=0 + sc + poly) + readout (+h for next layer) ----------------
template<int LAST>
__global__ __launch_bounds__(256) void k_node(const float* __restrict__ A, const float* __restrict__ nf,
        const float* __restrict__ attrs, const float* __restrict__ Wmix0, const float* __restrict__ Wsc,
        const float* __restrict__ Wprod, const float* __restrict__ Wtail, const float* __restrict__ Wml2,
        const float* __restrict__ Wup1, float* __restrict__ nf1out, float* __restrict__ hout,
        void* __restrict__ out, const int* __restrict__ flag){
    int wv = threadIdx.x >> 6;
    int n  = blockIdx.x * 4 + wv;
    int l  = threadIdx.x & 63;
    float Af  = A[n*64 + l];
    float nff = nf[n*64 + l];
    float am = 0.f;
    #pragma unroll 16
    for (int f = 0; f < 64; f++) am += __shfl(Af, f) * Wmix0[f*64 + l];
    float sc = 0.f;
    for (int s = 0; s < 10; s++){
        float av = attrs[n*10 + s];       // wave-uniform
        if (av != 0.f){
            const float* Ws = Wsc + s*4096;
            float t = 0.f;
            #pragma unroll 16
            for (int f = 0; f < 64; f++) t += __shfl(nff, f) * Ws[f*64 + l];
            sc += av * t;
        }
    }
    float poly = Wprod[l] + Wprod[64 + l]*am + Wprod[128 + l]*am*am;
    float val = am*poly + sc;
    float rv;
    if (LAST == 0){
        nf1out[n*64 + l] = val;
        float hv = 0.f;
        #pragma unroll 16
        for (int g = 0; g < 64; g++) hv += __shfl(val, g) * Wup1[g*64 + l];
        hout[n*64 + l] = hv;
        rv = val * Wtail[l];
    } else {
        int lj = l & 15;           // all 64 lanes run the shfl loop (divergent shfl is UB)
        float t = 0.f;
        #pragma unroll 16
        for (int g = 0; g < 64; g++){
            float vg = __shfl(val, g);
            t += vg * Wtail[g*16 + lj];
        }
        rv = (l < 16) ? (silu_f(t) * Wml2[lj]) : 0.f;
    }
    #pragma unroll
    for (int o2 = 32; o2; o2 >>= 1) rv += __shfl_down(rv, o2);
    if (l == 0){
        int idx = 2*n + LAST;
        if (flag[0] > 100) ((__hip_bfloat16*)out)[idx] = __float2bfloat16(rv);
        else               ((float*)out)[idx] = rv;
    }
}

// ---------------- launch ----------------
extern "C" void kernel_launch(void* const* d_in, const int* in_sizes, int n_in,
                              void* d_out, int out_size, void* d_ws, size_t ws_size,
                              hipStream_t stream) {
    int*   iw = (int*)d_ws;
    float* fw = (float*)d_ws;
    const int* snd = (const int*)d_in[3];
    const int* rcv = (const int*)d_in[4];

    PrepArgs pa;
    const int    pidx[21] = {0,1,2, 5,6,7,8,9,10,11,12,13,14,15,16,17,18,19,20,21,22};
    const size_t pdst[21] = {W_POS, W_ATT, W_SHF,
        W_WGT+OW_EMB, W_WGT+OW_UP0, W_WGT+OW_R10, W_WGT+OW_R20, W_WGT+OW_R30,
        W_WGT+OW_MIX0, W_WGT+OW_SC0, W_WGT+OW_PR0,
        W_WGT+OW_UP1, W_WGT+OW_R11, W_WGT+OW_R21, W_WGT+OW_R31,
        W_WGT+OW_MIX1, W_WGT+OW_SC1, W_WGT+OW_PR1,
        W_WGT+OW_RD0, W_WGT+OW_ML1, W_WGT+OW_ML2};
    const int    pn[21]   = {30000, 100000, 480000,
        640, 4096, 512, 4096, 16384, 16384, 40960, 192,
        4096, 512, 4096, 16384, 16384, 40960, 192, 64, 1024, 16};
    for (int i = 0; i < 21; i++){
        pa.s[i] = d_in[pidx[i]];
        pa.d[i] = fw + pdst[i];
        pa.n[i] = pn[i];
    }

    const int dual   = (ws_size >= NEED_DUAL);
    const int single = (!dual && ws_size >= NEED_SINGLE);
    const size_t wp  = dual ? WP_DUAL : WP_SINGLE;

    hipMemsetAsync(iw, 0, (W_CNT + NN) * sizeof(int), stream);   // flag + cnt
    k_detect<<<196, 256, 0, stream>>>((const uint32_t*)d_in[1], iw + W_FLAG);
    k_prep<<<120, 256, 0, stream>>>(pa, iw + W_FLAG);
    k_hist<<<NE/256, 256, 0, stream>>>(rcv, iw + W_CNT);
    k_scan<<<1, 1024, 0, stream>>>(iw + W_CNT, iw + W_OFFS, iw + W_CUR);
    k_scatter<<<NE/256, 256, 0, stream>>>(rcv, snd, iw + W_CUR, iw + W_SSND, iw + W_INV);
    if (dual || single){
        // rs overlays head of R0 (consumed by k_bess before k_mlp writes R0)
        float* rs = fw + W_R0;
        k_geom_r<<<NE/256, 256, 0, stream>>>(fw + W_POS, fw + W_SHF, snd, rcv, iw + W_INV, rs);
        k_bess<<<NE/256, 256, 0, stream>>>(rs, fw + W_BES);
        k_wpack<<<2, 256, 0, stream>>>(fw + W_WGT, (u16*)(fw + wp));
    } else {
        k_geom_full<<<NE/256, 256, 0, stream>>>(fw + W_POS, fw + W_SHF, snd, rcv, iw + W_INV, fw + W_BES);
    }
    k_embed_h<<<NN/4, 256, 0, stream>>>(fw + W_ATT, fw + W_WGT + OW_EMB, fw + W_WGT + OW_UP0,
                                        fw + W_NF0, fw + W_H);
    if (dual){
        k_mlp_mfma<<<1250, 256, 0, stream>>>(fw+W_BES, (const u16*)(fw + wp),
                                             (const u16*)(fw + wp) + 10400,
                                             (u16*)(fw + W_R0), (u16*)(fw + W_R1));
        k_gather<<<NN/4, 256, 0, stream>>>(iw+W_OFFS, iw+W_SSND, fw+W_H,
                                           (const u16*)(fw + W_R0), fw + W_A);
    } else if (single){
        k_mlp_mfma<<<625, 256, 0, stream>>>(fw+W_BES, (const u16*)(fw + wp),
                                            (const u16*)(fw + wp),
                                            (u16*)(fw + W_R0), (u16*)(fw + W_R0));
        k_gather<<<NN/4, 256, 0, stream>>>(iw+W_OFFS, iw+W_SSND, fw+W_H,
                                           (const u16*)(fw + W_R0), fw + W_A);
    } else {
        k_msg_fused<<<NN/4, 256, 0, stream>>>(iw+W_OFFS, iw+W_SSND, fw+W_H, fw+W_BES,
                                              fw+W_WGT+OW_R10, fw+W_WGT+OW_R20,
                                              fw+W_WGT+OW_R30, fw + W_A);
    }
    k_node<0><<<NN/4, 256, 0, stream>>>(fw + W_A, fw + W_NF0, fw + W_ATT,
                                        fw + W_WGT + OW_MIX0, fw + W_WGT + OW_SC0,
                                        fw + W_WGT + OW_PR0, fw + W_WGT + OW_RD0, nullptr,
                                        fw + W_WGT + OW_UP1, fw + W_NF1, fw + W_H,
                                        d_out, iw + W_FLAG);
    // ---- interaction 1 ----
    if (dual){
        k_gather<<<NN/4, 256, 0, stream>>>(iw+W_OFFS, iw+W_SSND, fw+W_H,
                                           (const u16*)(fw + W_R1), fw + W_A);
    } else if (single){
        k_mlp_mfma<<<625, 256, 0, stream>>>(fw+W_BES, (const u16*)(fw + wp) + 10400,
                                            (const u16*)(fw + wp) + 10400,
                                            (u16*)(fw + W_R0), (u16*)(fw + W_R0));
        k_gather<<<NN/4, 256, 0, stream>>>(iw+W_OFFS, iw+W_SSND, fw+W_H,
                                           (const u16*)(fw + W_R0), fw + W_A);
    } else {
        k_msg_fused<<<NN/4, 256, 0, stream>>>(iw+W_OFFS, iw+W_SSND, fw+W_H, fw+W_BES,
                                              fw+W_WGT+OW_R11, fw+W_WGT+OW_R21,
                                              fw+W_WGT+OW_R31, fw + W_A);
    }
    k_node<1><<<NN/4, 256, 0, stream>>>(fw + W_A, fw + W_NF1, fw + W_ATT,
                                        fw + W_WGT + OW_MIX1, fw + W_WGT + OW_SC1,
                                        fw + W_WGT + OW_PR1, fw + W_WGT + OW_ML1,
                                        fw + W_WGT + OW_ML2, nullptr, nullptr, nullptr,
                                        d_out, iw + W_FLAG);
}

// Round 13
// 241.480 us; speedup vs baseline: 5.0743x; 1.1453x over previous
//
#include <hip/hip_runtime.h>
#include <hip/hip_bf16.h>
#include <cstdint>
#include <cstddef>

#define NN 10000
#define NE 160000

typedef unsigned short u16;
typedef __attribute__((ext_vector_type(8))) short short8;
typedef __attribute__((ext_vector_type(4))) float f32x4;

__device__ __forceinline__ float b2f(u16 u){
    union { uint32_t i; float f; } v; v.i = ((uint32_t)u) << 16; return v.f;
}
__device__ __forceinline__ u16 f2b(float f){
    union { __hip_bfloat16 h; u16 u; } c; c.h = __float2bfloat16(f); return c.u;
}
__device__ __forceinline__ float silu_f(float x){ return x / (1.f + __expf(-x)); }
__device__ __forceinline__ float ldr(const void* p, int i, int bf){
    return bf ? b2f(((const u16*)p)[i]) : ((const float*)p)[i];
}

// ---------------- workspace layout (4-byte word offsets) ----------------
constexpr size_t W_FLAG = 0;                        // 16 (flag[0] = anomaly count)
constexpr size_t W_CNT  = 16;                       // 10000
constexpr size_t W_OFFS = 10016;                    // 10001
constexpr size_t W_CUR  = 20032;                    // 10000
constexpr size_t W_SSND = 30032;                    // 160000 (sender per sorted pos)
constexpr size_t W_ATT  = 350032;                   // 100000
constexpr size_t W_POS  = 450032;                   // 30000
constexpr size_t W_SHF  = 480032;                   // 480000
constexpr size_t W_WGT  = 960032;
constexpr size_t OW_EMB = 0;
constexpr size_t OW_UP0 = 640;
constexpr size_t OW_R10 = 4736;
constexpr size_t OW_R20 = 5248;
constexpr size_t OW_R30 = 9344;
constexpr size_t OW_MIX0= 25728;
constexpr size_t OW_SC0 = 42112;
constexpr size_t OW_PR0 = 83072;
constexpr size_t OW_UP1 = 83264;
constexpr size_t OW_R11 = 87360;
constexpr size_t OW_R21 = 87872;
constexpr size_t OW_R31 = 91968;
constexpr size_t OW_MIX1= 108352;
constexpr size_t OW_SC1 = 124736;
constexpr size_t OW_PR1 = 165696;
constexpr size_t OW_RD0 = 165888;
constexpr size_t OW_ML1 = 165952;
constexpr size_t OW_ML2 = 166976;
constexpr size_t OW_TEND = 167000;
constexpr size_t W_BES  = W_WGT + OW_TEND;          // [E][8] f32 (fallback tier only)
constexpr size_t W_NF0  = W_BES + (size_t)NE*8;     // [N,64]
constexpr size_t W_H    = W_NF0 + (size_t)NN*64;
constexpr size_t W_A    = W_H   + (size_t)NN*64;    // h1 buffer in fused path; A in fallback
constexpr size_t W_NF1  = W_A   + (size_t)NN*64;
constexpr size_t W_R0   = W_NF1 + (size_t)NN*64;    // [E][64] bf16, RECEIVER-SORTED
constexpr size_t W_R1   = W_R0  + (size_t)NE*32;
constexpr size_t WP_DUAL   = W_R1 + (size_t)NE*32;  // packed weights 2 x 10400 u16
constexpr size_t WP_SINGLE = W_R0 + (size_t)NE*32;
constexpr size_t W_RS_D = WP_DUAL   + 10400;        // sorted distances [E] f32
constexpr size_t W_RS_S = WP_SINGLE + 10400;
constexpr size_t W_RS_F = W_R0;                     // fallback: rs at R0 slot (no R in fallback)
constexpr size_t WP_F   = W_R0 + NE;                // fallback: dummy wpack target

constexpr size_t NEED_DUAL   = (W_RS_D + NE) * 4;   // ~61.5 MB (ws measured ~268 MB)
constexpr size_t NEED_SINGLE = (W_RS_S + NE) * 4;   // ~41.0 MB

constexpr int OCT  = 520;   // weight per-oct stride (u16)
constexpr int OCTS = 136;   // activation per-oct stride (u16), 16 rows

// ---------------- detect (dtype) + histogram, one grid ----------------
__global__ void k_dh(const uint32_t* __restrict__ attrs, const int* __restrict__ rcv,
                     int* __restrict__ flag, int* __restrict__ cnt){
    int i = blockIdx.x * 256 + threadIdx.x;          // 625*256 == NE
    int c = 0;
    if (i < 50000){
        uint32_t v = attrs[i];
        c = (v != 0u && v != 0x3F800000u) ? 1 : 0;
    }
    unsigned long long m = __ballot(c);
    if ((threadIdx.x & 63) == 0 && m)
        atomicAdd(flag, (int)__popcll(m));
    if (i < NE) atomicAdd(&cnt[rcv[i]], 1);
}

// ---------------- exclusive scan of cnt -> offs, cur ----------------
__global__ void k_scan(const int* __restrict__ cnt, int* __restrict__ offs, int* __restrict__ cur){
    __shared__ int cl[10000];
    __shared__ int part[1024];
    int t = threadIdx.x;
    for (int i = t; i < 10000; i += 1024) cl[i] = cnt[i];
    __syncthreads();
    int base = t * 10;
    int s = 0;
    #pragma unroll
    for (int i = 0; i < 10; i++) if (base + i < NN) s += cl[base + i];
    part[t] = s; __syncthreads();
    for (int d = 1; d < 1024; d <<= 1){
        int v = part[t];
        if (t >= d) v += part[t - d];
        __syncthreads();
        part[t] = v;
        __syncthreads();
    }
    int run = part[t] - s;
    #pragma unroll
    for (int i = 0; i < 10; i++){
        int idx = base + i;
        if (idx < NN){ offs[idx] = run; cur[idx] = run; run += cl[idx]; }
    }
    if (t == 1023) offs[NN] = part[1023];
}

// ---------------- scatter edge -> sorted slot; fused distance (raw inputs) ----------------
__global__ void k_scatter_r(const int* __restrict__ rcv, const int* __restrict__ snd,
        const void* __restrict__ posr, const void* __restrict__ shfr,
        int* __restrict__ cur, int* __restrict__ ssnd, float* __restrict__ rs,
        const int* __restrict__ flag){
    int e = blockIdx.x * 256 + threadIdx.x;
    if (e >= NE) return;
    int bf = flag[0] > 100;
    int r = rcv[e], s = snd[e];
    float vx = ldr(posr, r*3+0, bf) - ldr(posr, s*3+0, bf) + ldr(shfr, e*3+0, bf);
    float vy = ldr(posr, r*3+1, bf) - ldr(posr, s*3+1, bf) + ldr(shfr, e*3+1, bf);
    float vz = ldr(posr, r*3+2, bf) - ldr(posr, s*3+2, bf) + ldr(shfr, e*3+2, bf);
    float rr = sqrtf(vx*vx + vy*vy + vz*vz);
    int p = atomicAdd(&cur[r], 1);
    ssnd[p] = s;
    rs[p] = rr;
}

// ---------------- bessel expansion (fallback tier only) ----------------
__global__ void k_bess(const float* __restrict__ rs, float* __restrict__ bessp){
    int p = blockIdx.x * 256 + threadIdx.x;
    if (p >= NE) return;
    float rr = rs[p];
    float xr = rr * 0.1f;
    float x2 = xr*xr; float x5 = x2*x2*xr;
    float env = 1.f - 21.f*x5 + 35.f*x5*xr - 15.f*x5*x2;
    if (xr >= 1.f) env = 0.f;
    float scl = 0.4472135954999579f * env / (rr + 1e-9f);
    float b[8];
    #pragma unroll
    for (int n = 1; n <= 8; n++)
        b[n-1] = scl * sinf((float)n * 3.14159265358979323846f * rr * 0.1f);
    float4* be = (float4*)(bessp + (size_t)p*8);
    be[0] = make_float4(b[0], b[1], b[2], b[3]);
    be[1] = make_float4(b[4], b[5], b[6], b[7]);
}

// ---------------- mega-prep: convert (blk 0..119) + wpack (120..121) + embed+h (122..2621) ----------------
struct PrepArgs { const void* s[21]; float* d[21]; int n[21]; };
__global__ __launch_bounds__(256) void k_prep_all(PrepArgs a, const int* __restrict__ flag,
        u16* __restrict__ WP, float* __restrict__ nf0, float* __restrict__ h){
    int bf = flag[0] > 100;
    int t = threadIdx.x;
    if (blockIdx.x < 120){
        int stride = 120 * 256;
        int t0 = blockIdx.x * 256 + t;
        for (int k = 0; k < 21; k++){
            float* d = a.d[k]; int n = a.n[k];
            if (bf){
                const u16* s = (const u16*)a.s[k];
                for (int i = t0; i < n; i += stride) d[i] = b2f(s[i]);
            } else {
                const float* s = (const float*)a.s[k];
                for (int i = t0; i < n; i += stride) d[i] = s[i];
            }
        }
    } else if (blockIdx.x < 122){
        int b = blockIdx.x - 120;
        const void* W1 = a.s[b ? 12 : 5];
        const void* W2 = a.s[b ? 13 : 6];
        const void* W3 = a.s[b ? 14 : 7];
        u16* dst = WP + b * 10400;
        for (int i = t; i < 5200; i += 256) ((uint32_t*)dst)[i] = 0;
        __syncthreads();
        for (int i = t; i < 512; i += 256){
            int n = i >> 3, k = i & 7;
            dst[n*8 + k] = f2b(ldr(W1, k*64 + n, bf));
        }
        for (int i = t; i < 2048; i += 256){
            int k = (i >> 6) * 2, n = i & 63;
            uint32_t p2 = ((uint32_t)f2b(ldr(W2, (k+1)*64 + n, bf)) << 16) | f2b(ldr(W2, k*64 + n, bf));
            uint32_t p3 = ((uint32_t)f2b(ldr(W3, (k+1)*256 + 4*n, bf)) << 16) | f2b(ldr(W3, k*256 + 4*n, bf));
            *(uint32_t*)&dst[2080 + (k>>3)*OCT + n*8 + (k&7)] = p2;
            *(uint32_t*)&dst[6240 + (k>>3)*OCT + n*8 + (k&7)] = p3;
        }
    } else {
        int nb = blockIdx.x - 122;                 // [0, 2500)
        int n = nb*4 + (t >> 6);
        int l = t & 63;
        const void* attrs = a.s[1];
        const void* Wemb  = a.s[3];
        const void* Wup0  = a.s[4];
        float acc = 0.f;
        #pragma unroll
        for (int s = 0; s < 10; s++) acc += ldr(attrs, n*10 + s, bf) * ldr(Wemb, s*64 + l, bf);
        nf0[n*64 + l] = acc;
        float hv = 0.f;
        #pragma unroll 16
        for (int g = 0; g < 64; g++) hv += __shfl(acc, g) * ldr(Wup0, g*64 + l, bf);
        h[n*64 + l] = hv;
    }
}

// ---------------- MFMA radial MLP: block = 256 edges; bessel computed inline from rs ----------------
// Grid must be 2*nblk0 (dual) or nblk0 >= gridDim.x (single); nblk0 = NE/256 = 625 per half.
__global__ __launch_bounds__(256) void k_mlp_mfma(const float* __restrict__ rs,
        const u16* __restrict__ WPa, const u16* __restrict__ WPb,
        u16* __restrict__ R0, u16* __restrict__ R1, int nblk0){
    __shared__ __align__(16) u16 W[10400];
    __shared__ __align__(16) u16 X[4][20*OCTS];
    int half = blockIdx.x >= nblk0;
    int blk  = half ? blockIdx.x - nblk0 : blockIdx.x;
    const u16* WP = half ? WPb : WPa;
    u16* R = half ? R1 : R0;
    int t = threadIdx.x;
    int w = t >> 6, lane = t & 63;
    int q = lane >> 4, r = lane & 15;
    u16* Xw = &X[w][0];
    // stage pre-packed weights: 10400 u16 = 1300 uint4
    for (int i = t; i < 1300; i += 256) ((uint4*)W)[i] = ((const uint4*)WP)[i];
    // zero Xc octs 1..3 (K-padding), per-wave region
    {
        uint32_t* xz = (uint32_t*)(Xw + OCTS);
        for (int i = lane; i < 204; i += 64) xz[i] = 0;
    }
    __syncthreads();
    int pbase = blk * 256 + w * 64;
    #pragma unroll 1
    for (int st = 0; st < 4; st++){
        int pb = pbase + st * 16;
        // bessel inline: lane covers (edge = lane>>2, k = 2*(lane&3), +1)
        {
            float rr = rs[pb + (lane >> 2)];
            float xr = rr * 0.1f;
            float x2 = xr*xr, x5 = x2*x2*xr;
            float env = 1.f - 21.f*x5 + 35.f*x5*xr - 15.f*x5*x2;
            if (xr >= 1.f) env = 0.f;
            float scl = 0.4472135954999579f * env / (rr + 1e-9f);
            int k0 = (lane & 3) * 2;
            float b0 = scl * sinf((float)(k0+1) * 0.3141592653589793f * rr);
            float b1 = scl * sinf((float)(k0+2) * 0.3141592653589793f * rr);
            ((uint32_t*)Xw)[lane] = ((uint32_t)f2b(b1) << 16) | f2b(b0);
        }
        // ---- layer 1: K=8 (padded to 32) ----
        {
            short8 a = *(const short8*)&Xw[q*OCTS + r*8];
            #pragma unroll
            for (int nt = 0; nt < 4; nt++){
                short8 b = *(const short8*)&W[q*OCT + (nt*16 + r)*8];
                f32x4 c = {0.f, 0.f, 0.f, 0.f};
                c = __builtin_amdgcn_mfma_f32_16x16x32_bf16(a, b, c, 0, 0, 0);
                #pragma unroll
                for (int g = 0; g < 4; g++){
                    int e = q*4 + g;
                    int n = nt*16 + r;
                    Xw[(4 + (n>>3))*OCTS + e*8 + (n&7)] = f2b(silu_f(c[g]));
                }
            }
        }
        // ---- layer 2: K=64 ----
        {
            short8 a0 = *(const short8*)&Xw[(4+q)*OCTS + r*8];
            short8 a1 = *(const short8*)&Xw[(8+q)*OCTS + r*8];
            #pragma unroll
            for (int nt = 0; nt < 4; nt++){
                short8 b0 = *(const short8*)&W[2080 + q*OCT + (nt*16 + r)*8];
                short8 b1 = *(const short8*)&W[2080 + (4+q)*OCT + (nt*16 + r)*8];
                f32x4 c = {0.f, 0.f, 0.f, 0.f};
                c = __builtin_amdgcn_mfma_f32_16x16x32_bf16(a0, b0, c, 0, 0, 0);
                c = __builtin_amdgcn_mfma_f32_16x16x32_bf16(a1, b1, c, 0, 0, 0);
                #pragma unroll
                for (int g = 0; g < 4; g++){
                    int e = q*4 + g;
                    int n = nt*16 + r;
                    Xw[(12 + (n>>3))*OCTS + e*8 + (n&7)] = f2b(silu_f(c[g]));
                }
            }
        }
        // ---- layer 3: K=64, store R (bf16, receiver-sorted) ----
        {
            short8 a0 = *(const short8*)&Xw[(12+q)*OCTS + r*8];
            short8 a1 = *(const short8*)&Xw[(16+q)*OCTS + r*8];
            #pragma unroll
            for (int nt = 0; nt < 4; nt++){
                short8 b0 = *(const short8*)&W[6240 + q*OCT + (nt*16 + r)*8];
                short8 b1 = *(const short8*)&W[6240 + (4+q)*OCT + (nt*16 + r)*8];
                f32x4 c = {0.f, 0.f, 0.f, 0.f};
                c = __builtin_amdgcn_mfma_f32_16x16x32_bf16(a0, b0, c, 0, 0, 0);
                c = __builtin_amdgcn_mfma_f32_16x16x32_bf16(a1, b1, c, 0, 0, 0);
                #pragma unroll
                for (int g = 0; g < 4; g++){
                    int e = q*4 + g;
                    int n = nt*16 + r;
                    R[(size_t)(pb + e)*64 + n] = f2b(c[g]);
                }
            }
        }
    }
}

// ---------------- fused gather + node update + readout ----------------
template<int LAST>
__global__ __launch_bounds__(256) void k_gnode(const int* __restrict__ offs,
        const int* __restrict__ ssnd, const float* __restrict__ h, const u16* __restrict__ R,
        const float* __restrict__ nf, const float* __restrict__ attrs,
        const float* __restrict__ Wmix0, const float* __restrict__ Wsc,
        const float* __restrict__ Wprod, const float* __restrict__ Wtail,
        const float* __restrict__ Wml2, const float* __restrict__ Wup1,
        float* __restrict__ nf1out, float* __restrict__ hout,
        void* __restrict__ out, const int* __restrict__ flag){
    int wv = threadIdx.x >> 6;
    int n  = blockIdx.x * 4 + wv;
    int l  = threadIdx.x & 63;
    int beg = __builtin_amdgcn_readfirstlane(offs[n]);
    int end = __builtin_amdgcn_readfirstlane(offs[n+1]);
    float acc = 0.f;
    int p = beg;
    for (; p + 4 <= end; p += 4){
        int s0 = __builtin_amdgcn_readfirstlane(ssnd[p+0]);
        int s1 = __builtin_amdgcn_readfirstlane(ssnd[p+1]);
        int s2 = __builtin_amdgcn_readfirstlane(ssnd[p+2]);
        int s3 = __builtin_amdgcn_readfirstlane(ssnd[p+3]);
        float r0 = b2f(R[(size_t)(p+0)*64 + l]);
        float r1 = b2f(R[(size_t)(p+1)*64 + l]);
        float r2 = b2f(R[(size_t)(p+2)*64 + l]);
        float r3 = b2f(R[(size_t)(p+3)*64 + l]);
        acc += h[s0*64 + l]*r0 + h[s1*64 + l]*r1 + h[s2*64 + l]*r2 + h[s3*64 + l]*r3;
    }
    for (; p < end; p++){
        int s = __builtin_amdgcn_readfirstlane(ssnd[p]);
        acc += h[s*64 + l] * b2f(R[(size_t)p*64 + l]);
    }
    float Af  = acc * 0.0625f;
    float nff = nf[n*64 + l];
    float am = 0.f;
    #pragma unroll 16
    for (int f = 0; f < 64; f++) am += __shfl(Af, f) * Wmix0[f*64 + l];
    float sc = 0.f;
    for (int s = 0; s < 10; s++){
        float av = attrs[n*10 + s];       // wave-uniform
        if (av != 0.f){
            const float* Ws = Wsc + s*4096;
            float t = 0.f;
            #pragma unroll 16
            for (int f = 0; f < 64; f++) t += __shfl(nff, f) * Ws[f*64 + l];
            sc += av * t;
        }
    }
    float poly = Wprod[l] + Wprod[64 + l]*am + Wprod[128 + l]*am*am;
    float val = am*poly + sc;
    float rv;
    if (LAST == 0){
        nf1out[n*64 + l] = val;
        float hv = 0.f;
        #pragma unroll 16
        for (int g = 0; g < 64; g++) hv += __shfl(val, g) * Wup1[g*64 + l];
        hout[n*64 + l] = hv;              // separate buffer: h is still being gathered by other blocks
        rv = val * Wtail[l];
    } else {
        int lj = l & 15;                  // all 64 lanes run the shfl loop (divergent shfl is UB)
        float t = 0.f;
        #pragma unroll 16
        for (int g = 0; g < 64; g++){
            float vg = __shfl(val, g);
            t += vg * Wtail[g*16 + lj];
        }
        rv = (l < 16) ? (silu_f(t) * Wml2[lj]) : 0.f;
    }
    #pragma unroll
    for (int o2 = 32; o2; o2 >>= 1) rv += __shfl_down(rv, o2);
    if (l == 0){
        int idx = 2*n + LAST;
        if (flag[0] > 100) ((__hip_bfloat16*)out)[idx] = __float2bfloat16(rv);
        else               ((float*)out)[idx] = rv;
    }
}

// ---------------- legacy fused msg + node (fallback tier only) ----------------
__global__ __launch_bounds__(256) void k_msg_fused(const int* __restrict__ offs,
        const int* __restrict__ ssnd, const float* __restrict__ h, const float* __restrict__ bessp,
        const float* __restrict__ W1, const float* __restrict__ W2, const float* __restrict__ W3,
        float* __restrict__ A){
    int wv = threadIdx.x >> 6;
    int n  = blockIdx.x * 4 + wv;
    int l  = threadIdx.x & 63;
    float w1c[8];
    #pragma unroll
    for (int i = 0; i < 8; i++) w1c[i] = W1[i*64 + l];
    float w2c[64];
    #pragma unroll
    for (int j = 0; j < 64; j++) w2c[j] = W2[j*64 + l];
    float w3c[64];
    #pragma unroll
    for (int j = 0; j < 64; j++) w3c[j] = W3[j*256 + 4*l];
    float acc = 0.f;
    int beg = __builtin_amdgcn_readfirstlane(offs[n]);
    int end = __builtin_amdgcn_readfirstlane(offs[n+1]);
    for (int p = beg; p < end; p++){
        int s = __builtin_amdgcn_readfirstlane(ssnd[p]);
        const float* be = bessp + (size_t)p*8;
        float h1 = 0.f;
        #pragma unroll
        for (int i = 0; i < 8; i++) h1 += be[i] * w1c[i];
        h1 = silu_f(h1);
        float h2 = 0.f;
        #pragma unroll
        for (int j = 0; j < 64; j++) h2 += __shfl(h1, j) * w2c[j];
        h2 = silu_f(h2);
        float rr = 0.f;
        #pragma unroll
        for (int j = 0; j < 64; j++) rr += __shfl(h2, j) * w3c[j];
        acc += h[s*64 + l] * rr;
    }
    A[n*64 + l] = acc * 0.0625f;
}
template<int LAST>
__global__ __launch_bounds__(256) void k_node(const float* __restrict__ A, const float* __restrict__ nf,
        const float* __restrict__ attrs, const float* __restrict__ Wmix0, const float* __restrict__ Wsc,
        const float* __restrict__ Wprod, const float* __restrict__ Wtail, const float* __restrict__ Wml2,
        const float* __restrict__ Wup1, float* __restrict__ nf1out, float* __restrict__ hout,
        void* __restrict__ out, const int* __restrict__ flag){
    int wv = threadIdx.x >> 6;
    int n  = blockIdx.x * 4 + wv;
    int l  = threadIdx.x & 63;
    float Af  = A[n*64 + l];
    float nff = nf[n*64 + l];
    float am = 0.f;
    #pragma unroll 16
    for (int f = 0; f < 64; f++) am += __shfl(Af, f) * Wmix0[f*64 + l];
    float sc = 0.f;
    for (int s = 0; s < 10; s++){
        float av = attrs[n*10 + s];
        if (av != 0.f){
            const float* Ws = Wsc + s*4096;
            float t = 0.f;
            #pragma unroll 16
            for (int f = 0; f < 64; f++) t += __shfl(nff, f) * Ws[f*64 + l];
            sc += av * t;
        }
    }
    float poly = Wprod[l] + Wprod[64 + l]*am + Wprod[128 + l]*am*am;
    float val = am*poly + sc;
    float rv;
    if (LAST == 0){
        nf1out[n*64 + l] = val;
        float hv = 0.f;
        #pragma unroll 16
        for (int g = 0; g < 64; g++) hv += __shfl(val, g) * Wup1[g*64 + l];
        hout[n*64 + l] = hv;
        rv = val * Wtail[l];
    } else {
        int lj = l & 15;
        float t = 0.f;
        #pragma unroll 16
        for (int g = 0; g < 64; g++){
            float vg = __shfl(val, g);
            t += vg * Wtail[g*16 + lj];
        }
        rv = (l < 16) ? (silu_f(t) * Wml2[lj]) : 0.f;
    }
    #pragma unroll
    for (int o2 = 32; o2; o2 >>= 1) rv += __shfl_down(rv, o2);
    if (l == 0){
        int idx = 2*n + LAST;
        if (flag[0] > 100) ((__hip_bfloat16*)out)[idx] = __float2bfloat16(rv);
        else               ((float*)out)[idx] = rv;
    }
}

// ---------------- launch ----------------
extern "C" void kernel_launch(void* const* d_in, const int* in_sizes, int n_in,
                              void* d_out, int out_size, void* d_ws, size_t ws_size,
                              hipStream_t stream) {
    int*   iw = (int*)d_ws;
    float* fw = (float*)d_ws;
    const int* snd = (const int*)d_in[3];
    const int* rcv = (const int*)d_in[4];

    PrepArgs pa;
    const int    pidx[21] = {0,1,2, 5,6,7,8,9,10,11,12,13,14,15,16,17,18,19,20,21,22};
    const size_t pdst[21] = {W_POS, W_ATT, W_SHF,
        W_WGT+OW_EMB, W_WGT+OW_UP0, W_WGT+OW_R10, W_WGT+OW_R20, W_WGT+OW_R30,
        W_WGT+OW_MIX0, W_WGT+OW_SC0, W_WGT+OW_PR0,
        W_WGT+OW_UP1, W_WGT+OW_R11, W_WGT+OW_R21, W_WGT+OW_R31,
        W_WGT+OW_MIX1, W_WGT+OW_SC1, W_WGT+OW_PR1,
        W_WGT+OW_RD0, W_WGT+OW_ML1, W_WGT+OW_ML2};
    const int    pn[21]   = {30000, 100000, 480000,
        640, 4096, 512, 4096, 16384, 16384, 40960, 192,
        4096, 512, 4096, 16384, 16384, 40960, 192, 64, 1024, 16};
    for (int i = 0; i < 21; i++){
        pa.s[i] = d_in[pidx[i]];
        pa.d[i] = fw + pdst[i];
        pa.n[i] = pn[i];
    }

    const int dual   = (ws_size >= NEED_DUAL);
    const int single = (!dual && ws_size >= NEED_SINGLE);
    const size_t wp  = dual ? WP_DUAL : (single ? WP_SINGLE : WP_F);
    const size_t wrs = dual ? W_RS_D  : (single ? W_RS_S  : W_RS_F);

    hipMemsetAsync(iw, 0, (W_CNT + NN) * sizeof(int), stream);   // flag + cnt
    k_dh<<<NE/256, 256, 0, stream>>>((const uint32_t*)d_in[1], rcv, iw + W_FLAG, iw + W_CNT);
    k_scan<<<1, 1024, 0, stream>>>(iw + W_CNT, iw + W_OFFS, iw + W_CUR);
    k_scatter_r<<<NE/256, 256, 0, stream>>>(rcv, snd, d_in[0], d_in[2],
                                            iw + W_CUR, iw + W_SSND, fw + wrs, iw + W_FLAG);
    k_prep_all<<<2622, 256, 0, stream>>>(pa, iw + W_FLAG, (u16*)(fw + wp), fw + W_NF0, fw + W_H);

    if (dual){
        // 1250 blocks total: 625 per interaction (256 edges/block; NE/256 = 625).
        // Round-12 bug: launched 2500/nblk0=1250 -> OOB rs reads + R1 write race.
        k_mlp_mfma<<<1250, 256, 0, stream>>>(fw + wrs, (const u16*)(fw + wp),
                                             (const u16*)(fw + wp) + 10400,
                                             (u16*)(fw + W_R0), (u16*)(fw + W_R1), 625);
        k_gnode<0><<<NN/4, 256, 0, stream>>>(iw+W_OFFS, iw+W_SSND, fw+W_H, (const u16*)(fw+W_R0),
            fw+W_NF0, fw+W_ATT, fw+W_WGT+OW_MIX0, fw+W_WGT+OW_SC0, fw+W_WGT+OW_PR0,
            fw+W_WGT+OW_RD0, nullptr, fw+W_WGT+OW_UP1, fw+W_NF1, fw+W_A, d_out, iw+W_FLAG);
        k_gnode<1><<<NN/4, 256, 0, stream>>>(iw+W_OFFS, iw+W_SSND, fw+W_A, (const u16*)(fw+W_R1),
            fw+W_NF1, fw+W_ATT, fw+W_WGT+OW_MIX1, fw+W_WGT+OW_SC1, fw+W_WGT+OW_PR1,
            fw+W_WGT+OW_ML1, fw+W_WGT+OW_ML2, nullptr, nullptr, nullptr, d_out, iw+W_FLAG);
    } else if (single){
        k_mlp_mfma<<<625, 256, 0, stream>>>(fw + wrs, (const u16*)(fw + wp),
                                            (const u16*)(fw + wp),
                                            (u16*)(fw + W_R0), (u16*)(fw + W_R0), 2000000);
        k_gnode<0><<<NN/4, 256, 0, stream>>>(iw+W_OFFS, iw+W_SSND, fw+W_H, (const u16*)(fw+W_R0),
            fw+W_NF0, fw+W_ATT, fw+W_WGT+OW_MIX0, fw+W_WGT+OW_SC0, fw+W_WGT+OW_PR0,
            fw+W_WGT+OW_RD0, nullptr, fw+W_WGT+OW_UP1, fw+W_NF1, fw+W_A, d_out, iw+W_FLAG);
        k_mlp_mfma<<<625, 256, 0, stream>>>(fw + wrs, (const u16*)(fw + wp) + 10400,
                                            (const u16*)(fw + wp) + 10400,
                                            (u16*)(fw + W_R0), (u16*)(fw + W_R0), 2000000);
        k_gnode<1><<<NN/4, 256, 0, stream>>>(iw+W_OFFS, iw+W_SSND, fw+W_A, (const u16*)(fw+W_R0),
            fw+W_NF1, fw+W_ATT, fw+W_WGT+OW_MIX1, fw+W_WGT+OW_SC1, fw+W_WGT+OW_PR1,
            fw+W_WGT+OW_ML1, fw+W_WGT+OW_ML2, nullptr, nullptr, nullptr, d_out, iw+W_FLAG);
    } else {
        // fallback tier: bessel buffer + VALU msg kernels (rs lives at W_R0 slot)
        k_bess<<<NE/256, 256, 0, stream>>>(fw + wrs, fw + W_BES);
        k_msg_fused<<<NN/4, 256, 0, stream>>>(iw+W_OFFS, iw+W_SSND, fw+W_H, fw+W_BES,
                                              fw+W_WGT+OW_R10, fw+W_WGT+OW_R20,
                                              fw+W_WGT+OW_R30, fw + W_A);
        k_node<0><<<NN/4, 256, 0, stream>>>(fw + W_A, fw + W_NF0, fw + W_ATT,
                                            fw + W_WGT + OW_MIX0, fw + W_WGT + OW_SC0,
                                            fw + W_WGT + OW_PR0, fw + W_WGT + OW_RD0, nullptr,
                                            fw + W_WGT + OW_UP1, fw + W_NF1, fw + W_H,
                                            d_out, iw + W_FLAG);
        k_msg_fused<<<NN/4, 256, 0, stream>>>(iw+W_OFFS, iw+W_SSND, fw+W_H, fw+W_BES,
                                              fw+W_WGT+OW_R11, fw+W_WGT+OW_R21,
                                              fw+W_WGT+OW_R31, fw + W_A);
        k_node<1><<<NN/4, 256, 0, stream>>>(fw + W_A, fw + W_NF1, fw + W_ATT,
                                            fw + W_WGT + OW_MIX1, fw + W_WGT + OW_SC1,
                                            fw + W_WGT + OW_PR1, fw + W_WGT + OW_ML1,
                                            fw + W_WGT + OW_ML2, nullptr, nullptr, nullptr,
                                            d_out, iw + W_FLAG);
    }
}

// Round 14
// 226.289 us; speedup vs baseline: 5.4149x; 1.0671x over previous
//
#include <hip/hip_runtime.h>
#include <hip/hip_bf16.h>
#include <cstdint>
#include <cstddef>

#define NN 10000
#define NE 160000

typedef unsigned short u16;
typedef __attribute__((ext_vector_type(8))) short short8;
typedef __attribute__((ext_vector_type(4))) float f32x4;

__device__ __forceinline__ float b2f(u16 u){
    union { uint32_t i; float f; } v; v.i = ((uint32_t)u) << 16; return v.f;
}
__device__ __forceinline__ u16 f2b(float f){
    union { __hip_bfloat16 h; u16 u; } c; c.h = __float2bfloat16(f); return c.u;
}
__device__ __forceinline__ float silu_f(float x){ return x / (1.f + __expf(-x)); }
__device__ __forceinline__ float ldr(const void* p, int i, int bf){
    return bf ? b2f(((const u16*)p)[i]) : ((const float*)p)[i];
}

// ---------------- workspace layout (4-byte word offsets) ----------------
constexpr size_t W_FLAG = 0;                        // 16 (flag[0] = anomaly count)
constexpr size_t W_CNT  = 16;                       // 10000
constexpr size_t W_OFFS = 10016;                    // 10001
constexpr size_t W_CUR  = 20032;                    // 10000
constexpr size_t W_SSND = 30032;                    // 160000 (sender per sorted pos)
constexpr size_t W_ATT  = 350032;                   // 100000
constexpr size_t W_POS  = 450032;                   // 30000
constexpr size_t W_SHF  = 480032;                   // 480000
constexpr size_t W_WGT  = 960032;
constexpr size_t OW_EMB = 0;
constexpr size_t OW_UP0 = 640;
constexpr size_t OW_R10 = 4736;
constexpr size_t OW_R20 = 5248;
constexpr size_t OW_R30 = 9344;
constexpr size_t OW_MIX0= 25728;
constexpr size_t OW_SC0 = 42112;
constexpr size_t OW_PR0 = 83072;
constexpr size_t OW_UP1 = 83264;
constexpr size_t OW_R11 = 87360;
constexpr size_t OW_R21 = 87872;
constexpr size_t OW_R31 = 91968;
constexpr size_t OW_MIX1= 108352;
constexpr size_t OW_SC1 = 124736;
constexpr size_t OW_PR1 = 165696;
constexpr size_t OW_RD0 = 165888;
constexpr size_t OW_ML1 = 165952;
constexpr size_t OW_ML2 = 166976;
constexpr size_t OW_TEND = 167000;
constexpr size_t W_BES  = W_WGT + OW_TEND;          // [E][8] f32 (fallback tier only)
constexpr size_t W_NF0  = W_BES + (size_t)NE*8;     // [N,64]
constexpr size_t W_H    = W_NF0 + (size_t)NN*64;
constexpr size_t W_A    = W_H   + (size_t)NN*64;    // h1 buffer in fused path; A in fallback
constexpr size_t W_NF1  = W_A   + (size_t)NN*64;
constexpr size_t W_R0   = W_NF1 + (size_t)NN*64;    // [E][64] bf16, RECEIVER-SORTED
constexpr size_t W_R1   = W_R0  + (size_t)NE*32;
constexpr size_t WP_DUAL   = W_R1 + (size_t)NE*32;  // packed weights 2 x 10400 u16
constexpr size_t WP_SINGLE = W_R0 + (size_t)NE*32;
constexpr size_t W_RS_D = WP_DUAL   + 10400;        // sorted distances [E] f32
constexpr size_t W_RS_S = WP_SINGLE + 10400;
constexpr size_t W_RS_F = W_R0;                     // fallback: rs at R0 slot (no R in fallback)
constexpr size_t WP_F   = W_R0 + NE;                // fallback: dummy wpack target

constexpr size_t NEED_DUAL   = (W_RS_D + NE) * 4;   // ~61.5 MB (ws measured ~268 MB)
constexpr size_t NEED_SINGLE = (W_RS_S + NE) * 4;   // ~41.0 MB

constexpr int OCT  = 520;   // weight per-oct stride (u16)
constexpr int OCTS = 136;   // activation per-oct stride (u16), 16 rows

// ---------------- detect (dtype) + histogram, one grid ----------------
__global__ void k_dh(const uint32_t* __restrict__ attrs, const int* __restrict__ rcv,
                     int* __restrict__ flag, int* __restrict__ cnt){
    int i = blockIdx.x * 256 + threadIdx.x;          // 625*256 == NE
    int c = 0;
    if (i < 50000){
        uint32_t v = attrs[i];
        c = (v != 0u && v != 0x3F800000u) ? 1 : 0;
    }
    unsigned long long m = __ballot(c);
    if ((threadIdx.x & 63) == 0 && m)
        atomicAdd(flag, (int)__popcll(m));
    if (i < NE) atomicAdd(&cnt[rcv[i]], 1);
}

// ---------------- merged: scan (block 0) + convert (1..30) + wpack (31..32) + embed_h (33..657) ----------------
struct PrepArgs { const void* s[21]; float* d[21]; int n[21]; };
__global__ __launch_bounds__(1024) void k_scan_prep(PrepArgs a, const int* __restrict__ flag,
        const int* __restrict__ cnt, int* __restrict__ offs, int* __restrict__ cur,
        u16* __restrict__ WP, float* __restrict__ nf0, float* __restrict__ h){
    int bf = flag[0] > 100;
    int t = threadIdx.x;
    if (blockIdx.x == 0){
        __shared__ int cl[10000];
        __shared__ int part[1024];
        for (int i = t; i < 10000; i += 1024) cl[i] = cnt[i];
        __syncthreads();
        int base = t * 10;
        int s = 0;
        #pragma unroll
        for (int i = 0; i < 10; i++) if (base + i < NN) s += cl[base + i];
        part[t] = s; __syncthreads();
        for (int d = 1; d < 1024; d <<= 1){
            int v = part[t];
            if (t >= d) v += part[t - d];
            __syncthreads();
            part[t] = v;
            __syncthreads();
        }
        int run = part[t] - s;
        #pragma unroll
        for (int i = 0; i < 10; i++){
            int idx = base + i;
            if (idx < NN){ offs[idx] = run; cur[idx] = run; run += cl[idx]; }
        }
        if (t == 1023) offs[NN] = part[1023];
    } else if (blockIdx.x < 31){
        int stride = 30 * 1024;
        int t0 = (blockIdx.x - 1) * 1024 + t;
        for (int k = 0; k < 21; k++){
            float* d = a.d[k]; int n = a.n[k];
            if (bf){
                const u16* s = (const u16*)a.s[k];
                for (int i = t0; i < n; i += stride) d[i] = b2f(s[i]);
            } else {
                const float* s = (const float*)a.s[k];
                for (int i = t0; i < n; i += stride) d[i] = s[i];
            }
        }
    } else if (blockIdx.x < 33){
        int b = blockIdx.x - 31;
        const void* W1 = a.s[b ? 12 : 5];
        const void* W2 = a.s[b ? 13 : 6];
        const void* W3 = a.s[b ? 14 : 7];
        u16* dst = WP + b * 10400;
        for (int i = t; i < 5200; i += 1024) ((uint32_t*)dst)[i] = 0;
        __syncthreads();
        for (int i = t; i < 512; i += 1024){
            int n = i >> 3, k = i & 7;
            dst[n*8 + k] = f2b(ldr(W1, k*64 + n, bf));
        }
        for (int i = t; i < 2048; i += 1024){
            int k = (i >> 6) * 2, n = i & 63;
            uint32_t p2 = ((uint32_t)f2b(ldr(W2, (k+1)*64 + n, bf)) << 16) | f2b(ldr(W2, k*64 + n, bf));
            uint32_t p3 = ((uint32_t)f2b(ldr(W3, (k+1)*256 + 4*n, bf)) << 16) | f2b(ldr(W3, k*256 + 4*n, bf));
            *(uint32_t*)&dst[2080 + (k>>3)*OCT + n*8 + (k&7)] = p2;
            *(uint32_t*)&dst[6240 + (k>>3)*OCT + n*8 + (k&7)] = p3;
        }
    } else {
        int nb = blockIdx.x - 33;                  // [0, 625): 16 nodes per block
        int n = nb*16 + (t >> 6);
        int l = t & 63;
        const void* attrs = a.s[1];
        const void* Wemb  = a.s[3];
        const void* Wup0  = a.s[4];
        float acc = 0.f;
        #pragma unroll
        for (int s = 0; s < 10; s++) acc += ldr(attrs, n*10 + s, bf) * ldr(Wemb, s*64 + l, bf);
        nf0[n*64 + l] = acc;
        float hv = 0.f;
        #pragma unroll 16
        for (int g = 0; g < 64; g++) hv += __shfl(acc, g) * ldr(Wup0, g*64 + l, bf);
        h[n*64 + l] = hv;
    }
}

// ---------------- scatter edge -> sorted slot; fused distance (raw inputs) ----------------
__global__ void k_scatter_r(const int* __restrict__ rcv, const int* __restrict__ snd,
        const void* __restrict__ posr, const void* __restrict__ shfr,
        int* __restrict__ cur, int* __restrict__ ssnd, float* __restrict__ rs,
        const int* __restrict__ flag){
    int e = blockIdx.x * 256 + threadIdx.x;
    if (e >= NE) return;
    int bf = flag[0] > 100;
    int r = rcv[e], s = snd[e];
    float vx = ldr(posr, r*3+0, bf) - ldr(posr, s*3+0, bf) + ldr(shfr, e*3+0, bf);
    float vy = ldr(posr, r*3+1, bf) - ldr(posr, s*3+1, bf) + ldr(shfr, e*3+1, bf);
    float vz = ldr(posr, r*3+2, bf) - ldr(posr, s*3+2, bf) + ldr(shfr, e*3+2, bf);
    float rr = sqrtf(vx*vx + vy*vy + vz*vz);
    int p = atomicAdd(&cur[r], 1);
    ssnd[p] = s;
    rs[p] = rr;
}

// ---------------- bessel expansion (fallback tier only) ----------------
__global__ void k_bess(const float* __restrict__ rs, float* __restrict__ bessp){
    int p = blockIdx.x * 256 + threadIdx.x;
    if (p >= NE) return;
    float rr = rs[p];
    float xr = rr * 0.1f;
    float x2 = xr*xr; float x5 = x2*x2*xr;
    float env = 1.f - 21.f*x5 + 35.f*x5*xr - 15.f*x5*x2;
    if (xr >= 1.f) env = 0.f;
    float scl = 0.4472135954999579f * env / (rr + 1e-9f);
    float b[8];
    #pragma unroll
    for (int n = 1; n <= 8; n++)
        b[n-1] = scl * sinf((float)n * 3.14159265358979323846f * rr * 0.1f);
    float4* be = (float4*)(bessp + (size_t)p*8);
    be[0] = make_float4(b[0], b[1], b[2], b[3]);
    be[1] = make_float4(b[4], b[5], b[6], b[7]);
}

// ---------------- MFMA radial MLP: block = 256 edges; bessel computed inline from rs ----------------
// Grid must be 2*nblk0 (dual) or nblk0 >= gridDim.x (single); nblk0 = NE/256 = 625 per half.
__global__ __launch_bounds__(256) void k_mlp_mfma(const float* __restrict__ rs,
        const u16* __restrict__ WPa, const u16* __restrict__ WPb,
        u16* __restrict__ R0, u16* __restrict__ R1, int nblk0){
    __shared__ __align__(16) u16 W[10400];
    __shared__ __align__(16) u16 X[4][20*OCTS];
    int half = blockIdx.x >= nblk0;
    int blk  = half ? blockIdx.x - nblk0 : blockIdx.x;
    const u16* WP = half ? WPb : WPa;
    u16* R = half ? R1 : R0;
    int t = threadIdx.x;
    int w = t >> 6, lane = t & 63;
    int q = lane >> 4, r = lane & 15;
    u16* Xw = &X[w][0];
    // stage pre-packed weights: 10400 u16 = 1300 uint4
    for (int i = t; i < 1300; i += 256) ((uint4*)W)[i] = ((const uint4*)WP)[i];
    // zero Xc octs 1..3 (K-padding), per-wave region
    {
        uint32_t* xz = (uint32_t*)(Xw + OCTS);
        for (int i = lane; i < 204; i += 64) xz[i] = 0;
    }
    __syncthreads();
    int pbase = blk * 256 + w * 64;
    #pragma unroll 1
    for (int st = 0; st < 4; st++){
        int pb = pbase + st * 16;
        // bessel inline: lane covers (edge = lane>>2, k = 2*(lane&3), +1)
        {
            float rr = rs[pb + (lane >> 2)];
            float xr = rr * 0.1f;
            float x2 = xr*xr, x5 = x2*x2*xr;
            float env = 1.f - 21.f*x5 + 35.f*x5*xr - 15.f*x5*x2;
            if (xr >= 1.f) env = 0.f;
            float scl = 0.4472135954999579f * env / (rr + 1e-9f);
            int k0 = (lane & 3) * 2;
            float b0 = scl * __sinf((float)(k0+1) * 0.3141592653589793f * rr);
            float b1 = scl * __sinf((float)(k0+2) * 0.3141592653589793f * rr);
            ((uint32_t*)Xw)[lane] = ((uint32_t)f2b(b1) << 16) | f2b(b0);
        }
        // ---- layer 1: K=8 (padded to 32) ----
        {
            short8 a = *(const short8*)&Xw[q*OCTS + r*8];
            #pragma unroll
            for (int nt = 0; nt < 4; nt++){
                short8 b = *(const short8*)&W[q*OCT + (nt*16 + r)*8];
                f32x4 c = {0.f, 0.f, 0.f, 0.f};
                c = __builtin_amdgcn_mfma_f32_16x16x32_bf16(a, b, c, 0, 0, 0);
                #pragma unroll
                for (int g = 0; g < 4; g++){
                    int e = q*4 + g;
                    int n = nt*16 + r;
                    Xw[(4 + (n>>3))*OCTS + e*8 + (n&7)] = f2b(silu_f(c[g]));
                }
            }
        }
        // ---- layer 2: K=64 ----
        {
            short8 a0 = *(const short8*)&Xw[(4+q)*OCTS + r*8];
            short8 a1 = *(const short8*)&Xw[(8+q)*OCTS + r*8];
            #pragma unroll
            for (int nt = 0; nt < 4; nt++){
                short8 b0 = *(const short8*)&W[2080 + q*OCT + (nt*16 + r)*8];
                short8 b1 = *(const short8*)&W[2080 + (4+q)*OCT + (nt*16 + r)*8];
                f32x4 c = {0.f, 0.f, 0.f, 0.f};
                c = __builtin_amdgcn_mfma_f32_16x16x32_bf16(a0, b0, c, 0, 0, 0);
                c = __builtin_amdgcn_mfma_f32_16x16x32_bf16(a1, b1, c, 0, 0, 0);
                #pragma unroll
                for (int g = 0; g < 4; g++){
                    int e = q*4 + g;
                    int n = nt*16 + r;
                    Xw[(12 + (n>>3))*OCTS + e*8 + (n&7)] = f2b(silu_f(c[g]));
                }
            }
        }
        // ---- layer 3: K=64, store R (bf16, receiver-sorted) ----
        {
            short8 a0 = *(const short8*)&Xw[(12+q)*OCTS + r*8];
            short8 a1 = *(const short8*)&Xw[(16+q)*OCTS + r*8];
            #pragma unroll
            for (int nt = 0; nt < 4; nt++){
                short8 b0 = *(const short8*)&W[6240 + q*OCT + (nt*16 + r)*8];
                short8 b1 = *(const short8*)&W[6240 + (4+q)*OCT + (nt*16 + r)*8];
                f32x4 c = {0.f, 0.f, 0.f, 0.f};
                c = __builtin_amdgcn_mfma_f32_16x16x32_bf16(a0, b0, c, 0, 0, 0);
                c = __builtin_amdgcn_mfma_f32_16x16x32_bf16(a1, b1, c, 0, 0, 0);
                #pragma unroll
                for (int g = 0; g < 4; g++){
                    int e = q*4 + g;
                    int n = nt*16 + r;
                    R[(size_t)(pb + e)*64 + n] = f2b(c[g]);
                }
            }
        }
    }
}

// ---------------- fused gather + node update + readout ----------------
template<int LAST>
__global__ __launch_bounds__(256) void k_gnode(const int* __restrict__ offs,
        const int* __restrict__ ssnd, const float* __restrict__ h, const u16* __restrict__ R,
        const float* __restrict__ nf, const float* __restrict__ attrs,
        const float* __restrict__ Wmix0, const float* __restrict__ Wsc,
        const float* __restrict__ Wprod, const float* __restrict__ Wtail,
        const float* __restrict__ Wml2, const float* __restrict__ Wup1,
        float* __restrict__ nf1out, float* __restrict__ hout,
        void* __restrict__ out, const int* __restrict__ flag){
    int wv = threadIdx.x >> 6;
    int n  = blockIdx.x * 4 + wv;
    int l  = threadIdx.x & 63;
    int beg = __builtin_amdgcn_readfirstlane(offs[n]);
    int end = __builtin_amdgcn_readfirstlane(offs[n+1]);
    float acc = 0.f;
    int p = beg;
    for (; p + 4 <= end; p += 4){
        int s0 = __builtin_amdgcn_readfirstlane(ssnd[p+0]);
        int s1 = __builtin_amdgcn_readfirstlane(ssnd[p+1]);
        int s2 = __builtin_amdgcn_readfirstlane(ssnd[p+2]);
        int s3 = __builtin_amdgcn_readfirstlane(ssnd[p+3]);
        float r0 = b2f(R[(size_t)(p+0)*64 + l]);
        float r1 = b2f(R[(size_t)(p+1)*64 + l]);
        float r2 = b2f(R[(size_t)(p+2)*64 + l]);
        float r3 = b2f(R[(size_t)(p+3)*64 + l]);
        acc += h[s0*64 + l]*r0 + h[s1*64 + l]*r1 + h[s2*64 + l]*r2 + h[s3*64 + l]*r3;
    }
    for (; p < end; p++){
        int s = __builtin_amdgcn_readfirstlane(ssnd[p]);
        acc += h[s*64 + l] * b2f(R[(size_t)p*64 + l]);
    }
    float Af  = acc * 0.0625f;
    float nff = nf[n*64 + l];
    float am = 0.f;
    #pragma unroll 16
    for (int f = 0; f < 64; f++) am += __shfl(Af, f) * Wmix0[f*64 + l];
    float sc = 0.f;
    for (int s = 0; s < 10; s++){
        float av = attrs[n*10 + s];       // wave-uniform
        if (av != 0.f){
            const float* Ws = Wsc + s*4096;
            float t = 0.f;
            #pragma unroll 16
            for (int f = 0; f < 64; f++) t += __shfl(nff, f) * Ws[f*64 + l];
            sc += av * t;
        }
    }
    float poly = Wprod[l] + Wprod[64 + l]*am + Wprod[128 + l]*am*am;
    float val = am*poly + sc;
    float rv;
    if (LAST == 0){
        nf1out[n*64 + l] = val;
        float hv = 0.f;
        #pragma unroll 16
        for (int g = 0; g < 64; g++) hv += __shfl(val, g) * Wup1[g*64 + l];
        hout[n*64 + l] = hv;              // separate buffer: h is still being gathered by other blocks
        rv = val * Wtail[l];
    } else {
        int lj = l & 15;                  // all 64 lanes run the shfl loop (divergent shfl is UB)
        float t = 0.f;
        #pragma unroll 16
        for (int g = 0; g < 64; g++){
            float vg = __shfl(val, g);
            t += vg * Wtail[g*16 + lj];
        }
        rv = (l < 16) ? (silu_f(t) * Wml2[lj]) : 0.f;
    }
    #pragma unroll
    for (int o2 = 32; o2; o2 >>= 1) rv += __shfl_down(rv, o2);
    if (l == 0){
        int idx = 2*n + LAST;
        if (flag[0] > 100) ((__hip_bfloat16*)out)[idx] = __float2bfloat16(rv);
        else               ((float*)out)[idx] = rv;
    }
}

// ---------------- legacy fused msg + node (fallback tier only) ----------------
__global__ __launch_bounds__(256) void k_msg_fused(const int* __restrict__ offs,
        const int* __restrict__ ssnd, const float* __restrict__ h, const float* __restrict__ bessp,
        const float* __restrict__ W1, const float* __restrict__ W2, const float* __restrict__ W3,
        float* __restrict__ A){
    int wv = threadIdx.x >> 6;
    int n  = blockIdx.x * 4 + wv;
    int l  = threadIdx.x & 63;
    float w1c[8];
    #pragma unroll
    for (int i = 0; i < 8; i++) w1c[i] = W1[i*64 + l];
    float w2c[64];
    #pragma unroll
    for (int j = 0; j < 64; j++) w2c[j] = W2[j*64 + l];
    float w3c[64];
    #pragma unroll
    for (int j = 0; j < 64; j++) w3c[j] = W3[j*256 + 4*l];
    float acc = 0.f;
    int beg = __builtin_amdgcn_readfirstlane(offs[n]);
    int end = __builtin_amdgcn_readfirstlane(offs[n+1]);
    for (int p = beg; p < end; p++){
        int s = __builtin_amdgcn_readfirstlane(ssnd[p]);
        const float* be = bessp + (size_t)p*8;
        float h1 = 0.f;
        #pragma unroll
        for (int i = 0; i < 8; i++) h1 += be[i] * w1c[i];
        h1 = silu_f(h1);
        float h2 = 0.f;
        #pragma unroll
        for (int j = 0; j < 64; j++) h2 += __shfl(h1, j) * w2c[j];
        h2 = silu_f(h2);
        float rr = 0.f;
        #pragma unroll
        for (int j = 0; j < 64; j++) rr += __shfl(h2, j) * w3c[j];
        acc += h[s*64 + l] * rr;
    }
    A[n*64 + l] = acc * 0.0625f;
}
template<int LAST>
__global__ __launch_bounds__(256) void k_node(const float* __restrict__ A, const float* __restrict__ nf,
        const float* __restrict__ attrs, const float* __restrict__ Wmix0, const float* __restrict__ Wsc,
        const float* __restrict__ Wprod, const float* __restrict__ Wtail, const float* __restrict__ Wml2,
        const float* __restrict__ Wup1, float* __restrict__ nf1out, float* __restrict__ hout,
        void* __restrict__ out, const int* __restrict__ flag){
    int wv = threadIdx.x >> 6;
    int n  = blockIdx.x * 4 + wv;
    int l  = threadIdx.x & 63;
    float Af  = A[n*64 + l];
    float nff = nf[n*64 + l];
    float am = 0.f;
    #pragma unroll 16
    for (int f = 0; f < 64; f++) am += __shfl(Af, f) * Wmix0[f*64 + l];
    float sc = 0.f;
    for (int s = 0; s < 10; s++){
        float av = attrs[n*10 + s];
        if (av != 0.f){
            const float* Ws = Wsc + s*4096;
            float t = 0.f;
            #pragma unroll 16
            for (int f = 0; f < 64; f++) t += __shfl(nff, f) * Ws[f*64 + l];
            sc += av * t;
        }
    }
    float poly = Wprod[l] + Wprod[64 + l]*am + Wprod[128 + l]*am*am;
    float val = am*poly + sc;
    float rv;
    if (LAST == 0){
        nf1out[n*64 + l] = val;
        float hv = 0.f;
        #pragma unroll 16
        for (int g = 0; g < 64; g++) hv += __shfl(val, g) * Wup1[g*64 + l];
        hout[n*64 + l] = hv;
        rv = val * Wtail[l];
    } else {
        int lj = l & 15;
        float t = 0.f;
        #pragma unroll 16
        for (int g = 0; g < 64; g++){
            float vg = __shfl(val, g);
            t += vg * Wtail[g*16 + lj];
        }
        rv = (l < 16) ? (silu_f(t) * Wml2[lj]) : 0.f;
    }
    #pragma unroll
    for (int o2 = 32; o2; o2 >>= 1) rv += __shfl_down(rv, o2);
    if (l == 0){
        int idx = 2*n + LAST;
        if (flag[0] > 100) ((__hip_bfloat16*)out)[idx] = __float2bfloat16(rv);
        else               ((float*)out)[idx] = rv;
    }
}

// ---------------- launch ----------------
extern "C" void kernel_launch(void* const* d_in, const int* in_sizes, int n_in,
                              void* d_out, int out_size, void* d_ws, size_t ws_size,
                              hipStream_t stream) {
    int*   iw = (int*)d_ws;
    float* fw = (float*)d_ws;
    const int* snd = (const int*)d_in[3];
    const int* rcv = (const int*)d_in[4];

    PrepArgs pa;
    const int    pidx[21] = {0,1,2, 5,6,7,8,9,10,11,12,13,14,15,16,17,18,19,20,21,22};
    const size_t pdst[21] = {W_POS, W_ATT, W_SHF,
        W_WGT+OW_EMB, W_WGT+OW_UP0, W_WGT+OW_R10, W_WGT+OW_R20, W_WGT+OW_R30,
        W_WGT+OW_MIX0, W_WGT+OW_SC0, W_WGT+OW_PR0,
        W_WGT+OW_UP1, W_WGT+OW_R11, W_WGT+OW_R21, W_WGT+OW_R31,
        W_WGT+OW_MIX1, W_WGT+OW_SC1, W_WGT+OW_PR1,
        W_WGT+OW_RD0, W_WGT+OW_ML1, W_WGT+OW_ML2};
    const int    pn[21]   = {30000, 100000, 480000,
        640, 4096, 512, 4096, 16384, 16384, 40960, 192,
        4096, 512, 4096, 16384, 16384, 40960, 192, 64, 1024, 16};
    for (int i = 0; i < 21; i++){
        pa.s[i] = d_in[pidx[i]];
        pa.d[i] = fw + pdst[i];
        pa.n[i] = pn[i];
    }

    const int dual   = (ws_size >= NEED_DUAL);
    const int single = (!dual && ws_size >= NEED_SINGLE);
    const size_t wp  = dual ? WP_DUAL : (single ? WP_SINGLE : WP_F);
    const size_t wrs = dual ? W_RS_D  : (single ? W_RS_S  : W_RS_F);

    hipMemsetAsync(iw, 0, (W_CNT + NN) * sizeof(int), stream);   // flag + cnt
    k_dh<<<NE/256, 256, 0, stream>>>((const uint32_t*)d_in[1], rcv, iw + W_FLAG, iw + W_CNT);
    k_scan_prep<<<658, 1024, 0, stream>>>(pa, iw + W_FLAG, iw + W_CNT, iw + W_OFFS, iw + W_CUR,
                                          (u16*)(fw + wp), fw + W_NF0, fw + W_H);
    k_scatter_r<<<NE/256, 256, 0, stream>>>(rcv, snd, d_in[0], d_in[2],
                                            iw + W_CUR, iw + W_SSND, fw + wrs, iw + W_FLAG);

    if (dual){
        k_mlp_mfma<<<1250, 256, 0, stream>>>(fw + wrs, (const u16*)(fw + wp),
                                             (const u16*)(fw + wp) + 10400,
                                             (u16*)(fw + W_R0), (u16*)(fw + W_R1), 625);
        k_gnode<0><<<NN/4, 256, 0, stream>>>(iw+W_OFFS, iw+W_SSND, fw+W_H, (const u16*)(fw+W_R0),
            fw+W_NF0, fw+W_ATT, fw+W_WGT+OW_MIX0, fw+W_WGT+OW_SC0, fw+W_WGT+OW_PR0,
            fw+W_WGT+OW_RD0, nullptr, fw+W_WGT+OW_UP1, fw+W_NF1, fw+W_A, d_out, iw+W_FLAG);
        k_gnode<1><<<NN/4, 256, 0, stream>>>(iw+W_OFFS, iw+W_SSND, fw+W_A, (const u16*)(fw+W_R1),
            fw+W_NF1, fw+W_ATT, fw+W_WGT+OW_MIX1, fw+W_WGT+OW_SC1, fw+W_WGT+OW_PR1,
            fw+W_WGT+OW_ML1, fw+W_WGT+OW_ML2, nullptr, nullptr, nullptr, d_out, iw+W_FLAG);
    } else if (single){
        k_mlp_mfma<<<625, 256, 0, stream>>>(fw + wrs, (const u16*)(fw + wp),
                                            (const u16*)(fw + wp),
                                            (u16*)(fw + W_R0), (u16*)(fw + W_R0), 2000000);
        k_gnode<0><<<NN/4, 256, 0, stream>>>(iw+W_OFFS, iw+W_SSND, fw+W_H, (const u16*)(fw+W_R0),
            fw+W_NF0, fw+W_ATT, fw+W_WGT+OW_MIX0, fw+W_WGT+OW_SC0, fw+W_WGT+OW_PR0,
            fw+W_WGT+OW_RD0, nullptr, fw+W_WGT+OW_UP1, fw+W_NF1, fw+W_A, d_out, iw+W_FLAG);
        k_mlp_mfma<<<625, 256, 0, stream>>>(fw + wrs, (const u16*)(fw + wp) + 10400,
                                            (const u16*)(fw + wp) + 10400,
                                            (u16*)(fw + W_R0), (u16*)(fw + W_R0), 2000000);
        k_gnode<1><<<NN/4, 256, 0, stream>>>(iw+W_OFFS, iw+W_SSND, fw+W_A, (const u16*)(fw+W_R0),
            fw+W_NF1, fw+W_ATT, fw+W_WGT+OW_MIX1, fw+W_WGT+OW_SC1, fw+W_WGT+OW_PR1,
            fw+W_WGT+OW_ML1, fw+W_WGT+OW_ML2, nullptr, nullptr, nullptr, d_out, iw+W_FLAG);
    } else {
        // fallback tier: bessel buffer + VALU msg kernels (rs lives at W_R0 slot)
        k_bess<<<NE/256, 256, 0, stream>>>(fw + wrs, fw + W_BES);
        k_msg_fused<<<NN/4, 256, 0, stream>>>(iw+W_OFFS, iw+W_SSND, fw+W_H, fw+W_BES,
                                              fw+W_WGT+OW_R10, fw+W_WGT+OW_R20,
                                              fw+W_WGT+OW_R30, fw + W_A);
        k_node<0><<<NN/4, 256, 0, stream>>>(fw + W_A, fw + W_NF0, fw + W_ATT,
                                            fw + W_WGT + OW_MIX0, fw + W_WGT + OW_SC0,
                                            fw + W_WGT + OW_PR0, fw + W_WGT + OW_RD0, nullptr,
                                            fw + W_WGT + OW_UP1, fw + W_NF1, fw + W_H,
                                            d_out, iw + W_FLAG);
        k_msg_fused<<<NN/4, 256, 0, stream>>>(iw+W_OFFS, iw+W_SSND, fw+W_H, fw+W_BES,
                                              fw+W_WGT+OW_R11, fw+W_WGT+OW_R21,
                                              fw+W_WGT+OW_R31, fw + W_A);
        k_node<1><<<NN/4, 256, 0, stream>>>(fw + W_A, fw + W_NF1, fw + W_ATT,
                                            fw + W_WGT + OW_MIX1, fw + W_WGT + OW_SC1,
                                            fw + W_WGT + OW_PR1, fw + W_WGT + OW_ML1,
                                            fw + W_WGT + OW_ML2, nullptr, nullptr, nullptr,
                                            d_out, iw + W_FLAG);
    }
}